// Round 11
// baseline (221.374 us; speedup 1.0000x reference)
//
#include <hip/hip_runtime.h>
#include <math.h>

#define NBOX   4096
#define NTHR   1024
#define MAXDET 300
#define CAP    3968          // fallback path: boxes kept in LDS
#define NWORDS (NBOX / 32)
#define ROWW   64            // ull words per supmat row (4096 bits)
#define CTW    16            // col-tile width in words per supmat block

typedef unsigned long long ull;

__device__ __forceinline__ float clipf(float v, float hi) {
  return fminf(fmaxf(v, 0.0f), hi);
}

__device__ __forceinline__ float getimg(const int* img_i) {
  int iv = *img_i;
  return (iv > 0 && iv < (1 << 24)) ? (float)iv : __int_as_float(iv);
}

// =================== kernel A: keys + hybrid bitonic sort + fused prep ===================
struct SMA { ull skey[NBOX]; int vcount; };

__global__ __launch_bounds__(NTHR)
void sort_kernel(const float* __restrict__ scores,
                 const int*   __restrict__ labels,
                 const float* __restrict__ cls_w,
                 const float* __restrict__ boxes,
                 const int*   __restrict__ img_i,
                 int*    __restrict__ ws_sorted,
                 int*    __restrict__ ws_V,
                 int*    __restrict__ ws_done,
                 float4* __restrict__ obox,
                 float*  __restrict__ area,
                 int N)
{
  __shared__ SMA sm;
  const int b   = blockIdx.x;
  const int tid = threadIdx.x;
  const float* sc = scores + (size_t)b * N;
  const int*   lb = labels + (size_t)b * N;

  if (tid == 0) { sm.vcount = 0; ws_done[b] = 0; }   // reset per-call state
  for (int i = tid; i < NBOX; i += NTHR) {
    float s = sc[i];
    ull key = (ull)(0xFFFFFFFFu - (unsigned)i);
    if (s > 0.3f) {                       // SCORE_THRESHOLD, strict >
      float w = s * cls_w[lb[i]];
      unsigned ub = __float_as_uint(w);
      ub = (ub & 0x80000000u) ? ~ub : (ub | 0x80000000u);
      key |= ((ull)ub << 32);
    }
    sm.skey[i] = key;
  }
  __syncthreads();

  const int lane  = tid & 63;
  const int wbase = (tid >> 6) << 8;
  ull v0, v1, v2, v3;

  #define LOADV  { v0 = sm.skey[wbase      + lane]; v1 = sm.skey[wbase + 64 + lane]; \
                   v2 = sm.skey[wbase +128 + lane]; v3 = sm.skey[wbase +192 + lane]; }
  #define STOREV { sm.skey[wbase      + lane] = v0; sm.skey[wbase + 64 + lane] = v1; \
                   sm.skey[wbase +128 + lane] = v2; sm.skey[wbase +192 + lane] = v3; }
  #define CSWAP_REG(va, vb, eo) { int e_ = wbase + (eo) + lane;                      \
      if ((((e_) & k) == 0) ? ((va) < (vb)) : ((va) > (vb))) { ull t_ = (va); (va) = (vb); (vb) = t_; } }
  #define CSWAP_SHFL(vr, eo) { int e_ = wbase + (eo) + lane;                         \
      ull c_ = __shfl_xor((vr), j);                                                  \
      bool km_ = ((((e_) & k) == 0) == ((lane & j) == 0));                           \
      (vr) = km_ ? ((vr) > c_ ? (vr) : c_) : ((vr) < c_ ? (vr) : c_); }
  #define LOCALPHASES(jmax) {                                                        \
      for (int j = (jmax); j >= 1; j >>= 1) {                                        \
        if (j == 128)     { CSWAP_REG(v0, v2, 0);  CSWAP_REG(v1, v3, 64);  }         \
        else if (j == 64) { CSWAP_REG(v0, v1, 0);  CSWAP_REG(v2, v3, 128); }         \
        else { CSWAP_SHFL(v0, 0); CSWAP_SHFL(v1, 64); CSWAP_SHFL(v2, 128); CSWAP_SHFL(v3, 192); } } }

  LOADV;
  for (int k = 2; k <= 256; k <<= 1) { LOCALPHASES(k >> 1); }
  STOREV;
  __syncthreads();

  for (int k = 512; k <= NBOX; k <<= 1) {
    for (int j = k >> 1; j >= 256; j >>= 1) {
      for (int i = tid; i < NBOX; i += NTHR) {
        int l = i ^ j;
        if (l > i) {
          ull a = sm.skey[i], c = sm.skey[l];
          if (((i & k) == 0) ? (a < c) : (a > c)) { sm.skey[i] = c; sm.skey[l] = a; }
        }
      }
      __syncthreads();
    }
    LOADV;
    LOCALPHASES(128);
    STOREV;
    __syncthreads();
  }

  int* wsb = ws_sorted + (size_t)b * N;
  int vc = (int)((v0 >> 32) != 0) + (int)((v1 >> 32) != 0)
         + (int)((v2 >> 32) != 0) + (int)((v3 >> 32) != 0);
  atomicAdd(&sm.vcount, vc);

  // fused prep: gather clipped + class-offset boxes and areas in sorted order
  float fimg = getimg(img_i);
  float offs = fimg + 1.0f;
  const float4* bx4 = (const float4*)(boxes + (size_t)b * N * 4);
  float4* obx = obox + (size_t)b * NBOX;
  float*  oar = area + (size_t)b * NBOX;
  #define EMIT(vm, mo) {                                                   \
      int idx = wbase + (mo) + lane;                                       \
      unsigned orig = 0xFFFFFFFFu - (unsigned)((vm) & 0xFFFFFFFFull);      \
      wsb[idx] = (int)orig;                                                \
      float4 bb = bx4[orig];                                               \
      float off = (float)lb[orig] * offs;                                  \
      bb.x = clipf(bb.x, fimg) + off;                                      \
      bb.y = clipf(bb.y, fimg) + off;                                      \
      bb.z = clipf(bb.z, fimg) + off;                                      \
      bb.w = clipf(bb.w, fimg) + off;                                      \
      obx[idx] = bb;                                                       \
      oar[idx] = fmaxf(bb.z - bb.x, 0.0f) * fmaxf(bb.w - bb.y, 0.0f);      \
  }
  EMIT(v0, 0); EMIT(v1, 64); EMIT(v2, 128); EMIT(v3, 192);

  __syncthreads();
  if (tid == 0) ws_V[b] = sm.vcount;
}

// =================== kernel M: suppression matrix CHUNK (+ transposed diag) ===================
__global__ __launch_bounds__(256)
void supmat_chunk(const float4* __restrict__ obox,
                  const float*  __restrict__ area,
                  const float*  __restrict__ nms_th,
                  const int*    __restrict__ ws_V,
                  const int*    __restrict__ ws_done,
                  ull* __restrict__ supmat,
                  ull* __restrict__ diagT,
                  int c1_tiles, int wlo)
{
  __shared__ float4 cbox[CTW * 64];
  __shared__ float  carea[CTW * 64];
  __shared__ float4 rbox[64];
  __shared__ float  rarea[64];
  __shared__ ull    dT[4][64];

  const int b   = blockIdx.y;
  if (ws_done[b]) return;
  const int rt  = blockIdx.x % c1_tiles;
  const int g   = blockIdx.x / c1_tiles;
  const int tid = threadIdx.x;
  const int V   = ws_V[b];
  const int JW  = (V + 63) >> 6;

  const int wlo_g = wlo + g * CTW;
  const int w0 = (wlo_g > rt) ? wlo_g : rt;
  const int w1 = (wlo_g + CTW < JW) ? wlo_g + CTW : JW;
  if (rt >= JW || w0 >= w1) return;
  const bool hasdiag = (w0 == rt);     // this block computes the diag word of tile rt

  double xt = (double)(*nms_th);
  float  th = (float)(1.0 / (1.0 + exp(-xt)));

  const float4* ob = obox + (size_t)b * NBOX;
  const float*  ar = area + (size_t)b * NBOX;

  const int e1 = (w1 - w0) * 64;
  for (int e = tid; e < e1; e += 256) {
    cbox[e]  = ob[w0 * 64 + e];
    carea[e] = ar[w0 * 64 + e];
  }
  if (tid < 64) {
    rbox[tid]  = ob[rt * 64 + tid];
    rarea[tid] = ar[rt * 64 + tid];
  }
  __syncthreads();

  const int wave  = tid >> 6;
  const int lane  = tid & 63;
  const int rbase = wave * 16;
  ull* sb = supmat + (size_t)b * NBOX * ROWW;
  ull colpart = 0;                     // lane j's suppressed-by column bits (this wave's rows)

  for (int w = w0; w < w1; ++w) {
    const float4 bj = cbox[(w - w0) * 64 + lane];
    const float  aj = carea[(w - w0) * 64 + lane];
    const int    j  = w * 64 + lane;
    #pragma unroll 4
    for (int rr = 0; rr < 16; ++rr) {
      const int i = rt * 64 + rbase + rr;
      if (i >= V) break;
      const float4 bi = rbox[rbase + rr];
      const float  ai = rarea[rbase + rr];
      float xx1 = fmaxf(bi.x, bj.x);
      float yy1 = fmaxf(bi.y, bj.y);
      float xx2 = fminf(bi.z, bj.z);
      float yy2 = fminf(bi.w, bj.w);
      float inter = fmaxf(xx2 - xx1, 0.0f) * fmaxf(yy2 - yy1, 0.0f);
      float denom = ai + aj;           // ((areas[i]+areas[j]) - inter) + 1e-9, ref order
      denom = denom - inter;
      denom = denom + 1e-9f;
      float iou = inter / denom;
      bool cond = (iou > th) && (j > i);
      ull word = __ballot(cond);
      if (lane == 0) sb[(size_t)i * ROWW + w] = word;
      if (w == rt) colpart |= (cond ? (1ull << (rbase + rr)) : 0ull);
    }
  }

  if (hasdiag) {
    dT[wave][lane] = colpart;
    __syncthreads();
    if (tid < 64)
      diagT[(size_t)b * NBOX + rt * 64 + tid] =
          (dT[0][tid] | dT[1][tid]) | (dT[2][tid] | dT[3][tid]);
  }
}

// =================== kernel R: single-wave resolve CHUNK — no LDS staging, apply from L2 ===================
template <int W>   // W = t1 - t0 words (16 or 32)
__global__ __launch_bounds__(64)
void resolve_chunk(const int* __restrict__ ws_V,
                   const ull* __restrict__ supmat,
                   const ull* __restrict__ diagT,
                   int* __restrict__ ws_done,
                   int* __restrict__ ws_total,
                   int* __restrict__ ws_kept,
                   int* __restrict__ ws_K,
                   int t0, int t1)
{
  __shared__ ull kmask_sh[W];
  __shared__ int kept_sh[MAXDET];

  const int b = blockIdx.x;
  if (ws_done[b]) return;
  const int lane = threadIdx.x;       // single 64-lane wave
  const int V    = ws_V[b];
  const int JW   = (V + 63) >> 6;
  const ull* smat = supmat + (size_t)b * NBOX * ROWW;
  const ull* dTg  = diagT  + (size_t)b * NBOX;
  int* kg = ws_kept + (size_t)b * MAXDET;

  const int total_in = (t0 == 0) ? 0 : ws_total[b];

  // ---- catch-up (chunk>0): OR of prior kept rows, group-parallel + shfl reduce ----
  ull catchup = 0;
  if (t0 > 0) {
    const int G = 64 / W;
    int g = lane / W, w = lane % W;
    ull acc = 0;
    for (int k = g; k < total_in; k += G)
      acc |= smat[(size_t)kg[k] * ROWW + t0 + w];
    acc |= __shfl_xor(acc, W);
    if (G == 4) acc |= __shfl_xor(acc, 2 * W);
    catchup = acc;
  }

  // alive: lane w (<W) owns global word t0+w
  ull alive = 0;
  if (lane < W) {
    int lo = (t0 + lane) * 64;
    if (V > lo) { int n = V - lo; alive = (n >= 64) ? ~0ull : ((1ull << n) - 1ull); }
    alive &= ~catchup;
  }

  int total = total_in;
  const int tmax = (t1 < JW) ? t1 : JW;

  ull sdT = (t0 < tmax) ? dTg[t0 * 64 + lane] : 0ull;  // lane's suppressed-by mask, tile t0

  bool hit300 = false;
  int  tend   = t0;
  for (int t = t0; t < tmax; ++t) {
    ull pdT = 0;
    const bool pf = (t + 1 < tmax);
    if (pf) pdT = dTg[(t + 1) * 64 + lane];  // prefetch next diagT (in flight during walk)

    ull aw = __shfl(alive, t - t0);
    ull keptmask = 0;
    if (aw) {
      // ballot walk: sdT bit m = "lane suppressed by m" (precomputed transpose)
      ull rem = aw;
      bool done = false;
      while (rem) {
        int l = __builtin_ctzll(rem);
        rem &= rem - 1;
        keptmask |= (1ull << l);
        ++total;
        if (total == MAXDET) { done = true; break; }
        ull su = __ballot((sdT >> l) & 1ull);   // bit m = "m suppressed by kept l"
        rem &= ~su;
      }
      if (!done) {
        // apply kept rows to later words, straight from global (L2-resident rows,
        // 16 lanes x 8B = one 128B line per kept row, 4-acc ILP)
        if (lane < W) {
          const ull* colp = smat + t0 + lane;
          ull a0 = 0, a1 = 0, a2 = 0, a3 = 0;
          ull km = keptmask;
          while (km) {
            int l = __builtin_ctzll(km); km &= km - 1;
            a0 |= colp[(size_t)(t * 64 + l) * ROWW];
            if (km) { l = __builtin_ctzll(km); km &= km - 1; a1 |= colp[(size_t)(t * 64 + l) * ROWW]; }
            if (km) { l = __builtin_ctzll(km); km &= km - 1; a2 |= colp[(size_t)(t * 64 + l) * ROWW]; }
            if (km) { l = __builtin_ctzll(km); km &= km - 1; a3 |= colp[(size_t)(t * 64 + l) * ROWW]; }
          }
          if ((t0 + lane) > t) alive &= ~((a0 | a1) | (a2 | a3));
        }
      } else {
        hit300 = true;                 // wave-uniform
      }
    }
    if (lane == 0) kmask_sh[t - t0] = keptmask;
    tend = t + 1;
    if (hit300) break;
    sdT = pdT;
  }

  // ---- expand kept masks -> kept_sh (lane per tile, prefix scan) ----
  const int ntiles = tend - t0;
  {
    ull km = (lane < ntiles) ? kmask_sh[lane] : 0ull;
    int pc = __popcll(km);
    int incl = pc;
    #pragma unroll
    for (int s = 1; s < 64; s <<= 1) {
      int v = __shfl_up(incl, s);
      if (lane >= s) incl += v;
    }
    int base = total_in + incl - pc;
    while (km) {
      int l = __builtin_ctzll(km);
      km &= km - 1;
      kept_sh[base++] = (t0 + lane) * 64 + l;
    }
  }

  const int K = total;                 // wave-uniform
  for (int rI = total_in + lane; rI < K; rI += 64) kg[rI] = kept_sh[rI];

  const bool finished = hit300 || (t1 >= JW);
  if (!finished) {
    if (lane == 0) ws_total[b] = K;
    return;
  }
  if (lane == 0) { ws_done[b] = 1; ws_K[b] = K; }
}

// =================== kernel O: gather + write outputs ===================
__global__ __launch_bounds__(256)
void write_out(const float* __restrict__ boxes,
               const float* __restrict__ scores,
               const int*   __restrict__ labels,
               const int*   __restrict__ img_i,
               float* __restrict__ out,
               int B, int N,
               const int* __restrict__ ws_sorted,
               const int* __restrict__ ws_K,
               const int* __restrict__ ws_kept)
{
  const int b   = blockIdx.x;
  const int tid = threadIdx.x;
  const int K   = ws_K[b];
  const int* kg = ws_kept + (size_t)b * MAXDET;

  float fimg = getimg(img_i);
  const float* bx = boxes  + (size_t)b * N * 4;
  const float* sc = scores + (size_t)b * N;
  const int*   lb = labels + (size_t)b * N;
  const int*   so = ws_sorted + (size_t)b * N;

  float4* obx = (float4*)out;
  float*  osc = out + (size_t)B * MAXDET * 4;
  float*  olb = osc + (size_t)B * MAXDET;
  float*  ovl = olb + (size_t)B * MAXDET;
  for (int rI = tid; rI < MAXDET; rI += 256) {
    size_t slot = (size_t)b * MAXDET + rI;
    if (rI < K) {
      int i    = kg[rI];
      int orig = so[i];
      float4 bb = ((const float4*)bx)[orig];
      bb.x = clipf(bb.x, fimg);
      bb.y = clipf(bb.y, fimg);
      bb.z = clipf(bb.z, fimg);
      bb.w = clipf(bb.w, fimg);
      obx[slot] = bb;
      osc[slot] = sc[orig];
      olb[slot] = (float)lb[orig];
      ovl[slot] = 1.0f;
    } else {
      obx[slot] = make_float4(0.f, 0.f, 0.f, 0.f);
      osc[slot] = 0.0f;
      olb[slot] = 0.0f;
      ovl[slot] = 0.0f;
    }
  }
}

// =================== fallback kernel (round-2 path, used if ws too small) ===================
struct SMB {
  float4       obox[CAP];
  unsigned int keepw[NWORDS];
  int          kept_pos[MAXDET];
  int          scal[4];
};

__global__ __launch_bounds__(NTHR)
void nms_kernel(const float* __restrict__ boxes,
                const float* __restrict__ scores,
                const int*   __restrict__ labels,
                const float* __restrict__ nms_th,
                const float* __restrict__ cls_w,
                const int*   __restrict__ img_i,
                float* __restrict__ out,
                int B, int N,
                const int* __restrict__ ws_sorted,
                const int* __restrict__ ws_V,
                float4* __restrict__ ws_ovf)
{
  __shared__ SMB sm;
  const int b    = blockIdx.x;
  const int tid  = threadIdx.x;

  const float* bx = boxes  + (size_t)b * N * 4;
  const float* sc = scores + (size_t)b * N;
  const int*   lb = labels + (size_t)b * N;
  const int*   so = ws_sorted + (size_t)b * N;

  float fimg = getimg(img_i);
  float off_scale = fimg + 1.0f;
  double xt = (double)(*nms_th);
  float  th = (float)(1.0 / (1.0 + exp(-xt)));

  const int V = ws_V[b];
  if (tid < 4) sm.scal[tid] = 0;

  for (int m = 0; m < 4; ++m) {
    int i = tid + m * NTHR;
    int orig = so[i];
    float4 bb = ((const float4*)bx)[orig];
    float off = (float)lb[orig] * off_scale;
    bb.x = clipf(bb.x, fimg) + off;
    bb.y = clipf(bb.y, fimg) + off;
    bb.z = clipf(bb.z, fimg) + off;
    bb.w = clipf(bb.w, fimg) + off;
    if (i < CAP) sm.obox[i] = bb;
    else         ws_ovf[(size_t)b * (NBOX - CAP) + (i - CAP)] = bb;
  }
  for (int w = tid; w < NWORDS; w += NTHR) {
    int lo = w * 32;
    unsigned val;
    if      (V >= lo + 32) val = 0xFFFFFFFFu;
    else if (V <= lo)      val = 0u;
    else                   val = (1u << (V - lo)) - 1u;
    sm.keepw[w] = val;
  }
  __syncthreads();

  const int nt = (V + 63) >> 6;
  int TR = 0;
  for (int t = 0; t < nt; ++t) {
    if (tid < 64) {
      int i0 = t * 64;
      int me = i0 + tid;
      float4 bb = (me < CAP) ? sm.obox[me]
                             : ws_ovf[(size_t)b * (NBOX - CAP) + (me - CAP)];
      float arJ = fmaxf(bb.z - bb.x, 0.0f) * fmaxf(bb.w - bb.y, 0.0f);
      ull supby = 0;
      for (int l = 0; l < 64; ++l) {
        int i = i0 + l;
        float4 bi = (i < CAP) ? sm.obox[i]
                              : ws_ovf[(size_t)b * (NBOX - CAP) + (i - CAP)];
        float ai = fmaxf(bi.z - bi.x, 0.0f) * fmaxf(bi.w - bi.y, 0.0f);
        float xx1 = fmaxf(bi.x, bb.x);
        float yy1 = fmaxf(bi.y, bb.y);
        float xx2 = fminf(bi.z, bb.z);
        float yy2 = fminf(bi.w, bb.w);
        float inter = fmaxf(xx2 - xx1, 0.0f) * fmaxf(yy2 - yy1, 0.0f);
        float denom = ai + arJ;
        denom = denom - inter;
        denom = denom + 1e-9f;
        float iou = inter / denom;
        if (iou > th) supby |= (1ull << l);
      }
      ull alive = ((ull)sm.keepw[2 * t + 1] << 32) | sm.keepw[2 * t];
      ull rem = alive;
      while (rem) {
        int l = __builtin_ctzll(rem);
        rem &= rem - 1;
        ull sup = __ballot((supby >> l) & 1ull);
        sup &= ((~1ull) << l);
        sup &= alive;
        alive &= ~sup;
        rem   &= ~sup;
      }
      if (tid == 0) {
        sm.keepw[2 * t]     = (unsigned)alive;
        sm.keepw[2 * t + 1] = (unsigned)(alive >> 32);
        atomicAdd(&sm.scal[1], __builtin_popcountll(alive));
      }
    }
    __syncthreads();
    TR = t + 1;
    if (sm.scal[1] >= MAXDET) break;

    int jstart = (t + 1) * 64;
    if (jstart < V) {
      ull alive = ((ull)sm.keepw[2 * t + 1] << 32) | sm.keepw[2 * t];
      if (alive) {
        for (int j = jstart + tid; j < V; j += NTHR) {
          unsigned wj = sm.keepw[j >> 5];
          if (!((wj >> (j & 31)) & 1u)) continue;
          float4 bj = (j < CAP) ? sm.obox[j]
                                : ws_ovf[(size_t)b * (NBOX - CAP) + (j - CAP)];
          float aj = fmaxf(bj.z - bj.x, 0.0f) * fmaxf(bj.w - bj.y, 0.0f);
          ull rem = alive;
          bool suppressed = false;
          while (rem) {
            int l = __builtin_ctzll(rem);
            rem &= rem - 1;
            int i = t * 64 + l;
            float4 bi = (i < CAP) ? sm.obox[i]
                                  : ws_ovf[(size_t)b * (NBOX - CAP) + (i - CAP)];
            float ai = fmaxf(bi.z - bi.x, 0.0f) * fmaxf(bi.w - bi.y, 0.0f);
            float xx1 = fmaxf(bi.x, bj.x);
            float yy1 = fmaxf(bi.y, bj.y);
            float xx2 = fminf(bi.z, bj.z);
            float yy2 = fminf(bi.w, bj.w);
            float inter = fmaxf(xx2 - xx1, 0.0f) * fmaxf(yy2 - yy1, 0.0f);
            float denom = ai + aj;
            denom = denom - inter;
            denom = denom + 1e-9f;
            float iou = inter / denom;
            if (iou > th) { suppressed = true; break; }
          }
          if (suppressed) atomicAnd(&sm.keepw[j >> 5], ~(1u << (j & 31)));
        }
      }
    }
    __syncthreads();
  }

  if (tid < NWORDS && tid >= TR * 2) sm.keepw[tid] = 0;
  __syncthreads();
  if (tid == 0) {
    int r = 0;
    for (int w = 0; w < NWORDS && r < MAXDET; ++w) {
      unsigned bits = sm.keepw[w];
      while (bits && r < MAXDET) {
        int l = __builtin_ctz(bits);
        bits &= bits - 1;
        sm.kept_pos[r++] = w * 32 + l;
      }
    }
    sm.scal[3] = r;
  }
  __syncthreads();
  const int K = sm.scal[3];

  float4* obx = (float4*)out;
  float*  osc = out + (size_t)B * MAXDET * 4;
  float*  olb = osc + (size_t)B * MAXDET;
  float*  ovl = olb + (size_t)B * MAXDET;
  for (int r = tid; r < MAXDET; r += NTHR) {
    size_t slot = (size_t)b * MAXDET + r;
    if (r < K) {
      int i    = sm.kept_pos[r];
      int orig = so[i];
      float4 bb = ((const float4*)bx)[orig];
      bb.x = clipf(bb.x, fimg);
      bb.y = clipf(bb.y, fimg);
      bb.z = clipf(bb.z, fimg);
      bb.w = clipf(bb.w, fimg);
      obx[slot] = bb;
      osc[slot] = sc[orig];
      olb[slot] = (float)lb[orig];
      ovl[slot] = 1.0f;
    } else {
      obx[slot] = make_float4(0.f, 0.f, 0.f, 0.f);
      osc[slot] = 0.0f;
      olb[slot] = 0.0f;
      ovl[slot] = 0.0f;
    }
  }
}

extern "C" void kernel_launch(void* const* d_in, const int* in_sizes, int n_in,
                              void* d_out, int out_size, void* d_ws, size_t ws_size,
                              hipStream_t stream) {
  const float* boxes      = (const float*)d_in[0];
  const float* scores     = (const float*)d_in[1];
  const int*   labels     = (const int*)d_in[2];
  const float* nms_thresh = (const float*)d_in[3];
  const float* cls_w      = (const float*)d_in[4];
  const int*   img_sz     = (const int*)d_in[5];

  int B = out_size / (MAXDET * 7);
  int N = in_sizes[1] / B;               // 4096

  // ws layout
  size_t sz_sorted = (size_t)B * N * 4;
  size_t off_V     = sz_sorted;
  size_t off_obox  = sz_sorted + 1024;
  size_t sz_obox   = (size_t)B * NBOX * 16;
  size_t off_area  = off_obox + sz_obox;
  size_t sz_area   = (size_t)B * NBOX * 4;
  size_t off_done  = (off_area + sz_area + 255) & ~(size_t)255;
  size_t off_total = off_done + (size_t)B * 4;
  size_t off_Kf    = off_total + (size_t)B * 4;
  size_t off_kept  = off_Kf + (size_t)B * 4;
  size_t off_dT    = (off_kept + (size_t)B * MAXDET * 4 + 255) & ~(size_t)255;
  size_t sz_dT     = (size_t)B * NBOX * 8;          // 512 KiB
  size_t off_sup   = (off_dT + sz_dT + 255) & ~(size_t)255;
  size_t sz_sup    = (size_t)B * NBOX * ROWW * 8;   // 32 MiB at B=16
  size_t need_fast = off_sup + sz_sup;

  int*    ws_sorted = (int*)d_ws;
  int*    ws_V      = (int*)((char*)d_ws + off_V);
  int*    ws_done   = (int*)((char*)d_ws + off_done);
  float4* obox      = (float4*)((char*)d_ws + off_obox);
  float*  area      = (float*)((char*)d_ws + off_area);

  sort_kernel<<<dim3(B), dim3(NTHR), 0, stream>>>(
      scores, labels, cls_w, boxes, img_sz,
      ws_sorted, ws_V, ws_done, obox, area, N);

  if (ws_size >= need_fast && N == NBOX) {
    int* ws_total = (int*)((char*)d_ws + off_total);
    int* ws_K     = (int*)((char*)d_ws + off_Kf);
    int* ws_kept  = (int*)((char*)d_ws + off_kept);
    ull* diagT    = (ull*)((char*)d_ws + off_dT);
    ull* supmat   = (ull*)((char*)d_ws + off_sup);

    // chunk 0: tiles [0,16)
    supmat_chunk<<<dim3(16, B), dim3(256), 0, stream>>>(
        obox, area, nms_thresh, ws_V, ws_done, supmat, diagT, 16, 0);
    resolve_chunk<16><<<dim3(B), dim3(64), 0, stream>>>(
        ws_V, supmat, diagT, ws_done, ws_total, ws_kept, ws_K, 0, 16);

    // chunk 1: tiles [16,32)
    supmat_chunk<<<dim3(32, B), dim3(256), 0, stream>>>(
        obox, area, nms_thresh, ws_V, ws_done, supmat, diagT, 32, 16);
    resolve_chunk<16><<<dim3(B), dim3(64), 0, stream>>>(
        ws_V, supmat, diagT, ws_done, ws_total, ws_kept, ws_K, 16, 32);

    // chunk 2: tiles [32,64)
    supmat_chunk<<<dim3(128, B), dim3(256), 0, stream>>>(
        obox, area, nms_thresh, ws_V, ws_done, supmat, diagT, 64, 32);
    resolve_chunk<32><<<dim3(B), dim3(64), 0, stream>>>(
        ws_V, supmat, diagT, ws_done, ws_total, ws_kept, ws_K, 32, 64);

    // final: gather + write all outputs
    write_out<<<dim3(B), dim3(256), 0, stream>>>(
        boxes, scores, labels, img_sz, (float*)d_out, B, N,
        ws_sorted, ws_K, ws_kept);
  } else {
    float4* ws_ovf = (float4*)((char*)d_ws + off_done + 1024);
    nms_kernel<<<dim3(B), dim3(NTHR), 0, stream>>>(boxes, scores, labels,
                                                   nms_thresh, cls_w, img_sz,
                                                   (float*)d_out, B, N,
                                                   ws_sorted, ws_V, ws_ovf);
  }
}

// Round 12
// 99.430 us; speedup vs baseline: 2.2264x; 2.2264x over previous
//
#include <hip/hip_runtime.h>
#include <math.h>

#define NBOX   4096
#define NTHR   1024
#define MAXDET 300
#define CAP    3968          // fallback path: boxes kept in LDS
#define NWORDS (NBOX / 32)

typedef unsigned long long ull;

__device__ __forceinline__ float clipf(float v, float hi) {
  return fminf(fmaxf(v, 0.0f), hi);
}

__device__ __forceinline__ float getimg(const int* img_i) {
  int iv = *img_i;
  return (iv > 0 && iv < (1 << 24)) ? (float)iv : __int_as_float(iv);
}

// =================== kernel A: keys + hybrid bitonic sort + fused prep ===================
struct SMA { ull skey[NBOX]; int vcount; };

__global__ __launch_bounds__(NTHR)
void sort_kernel(const float* __restrict__ scores,
                 const int*   __restrict__ labels,
                 const float* __restrict__ cls_w,
                 const float* __restrict__ boxes,
                 const int*   __restrict__ img_i,
                 int*    __restrict__ ws_sorted,
                 int*    __restrict__ ws_V,
                 int*    __restrict__ ws_done,
                 float4* __restrict__ obox,
                 float*  __restrict__ area,
                 int N)
{
  __shared__ SMA sm;
  const int b   = blockIdx.x;
  const int tid = threadIdx.x;
  const float* sc = scores + (size_t)b * N;
  const int*   lb = labels + (size_t)b * N;

  if (tid == 0) { sm.vcount = 0; ws_done[b] = 0; }   // reset per-call state
  for (int i = tid; i < NBOX; i += NTHR) {
    float s = sc[i];
    ull key = (ull)(0xFFFFFFFFu - (unsigned)i);
    if (s > 0.3f) {                       // SCORE_THRESHOLD, strict >
      float w = s * cls_w[lb[i]];
      unsigned ub = __float_as_uint(w);
      ub = (ub & 0x80000000u) ? ~ub : (ub | 0x80000000u);
      key |= ((ull)ub << 32);
    }
    sm.skey[i] = key;
  }
  __syncthreads();

  const int lane  = tid & 63;
  const int wbase = (tid >> 6) << 8;
  ull v0, v1, v2, v3;

  #define LOADV  { v0 = sm.skey[wbase      + lane]; v1 = sm.skey[wbase + 64 + lane]; \
                   v2 = sm.skey[wbase +128 + lane]; v3 = sm.skey[wbase +192 + lane]; }
  #define STOREV { sm.skey[wbase      + lane] = v0; sm.skey[wbase + 64 + lane] = v1; \
                   sm.skey[wbase +128 + lane] = v2; sm.skey[wbase +192 + lane] = v3; }
  #define CSWAP_REG(va, vb, eo) { int e_ = wbase + (eo) + lane;                      \
      if ((((e_) & k) == 0) ? ((va) < (vb)) : ((va) > (vb))) { ull t_ = (va); (va) = (vb); (vb) = t_; } }
  #define CSWAP_SHFL(vr, eo) { int e_ = wbase + (eo) + lane;                         \
      ull c_ = __shfl_xor((vr), j);                                                  \
      bool km_ = ((((e_) & k) == 0) == ((lane & j) == 0));                           \
      (vr) = km_ ? ((vr) > c_ ? (vr) : c_) : ((vr) < c_ ? (vr) : c_); }
  #define LOCALPHASES(jmax) {                                                        \
      for (int j = (jmax); j >= 1; j >>= 1) {                                        \
        if (j == 128)     { CSWAP_REG(v0, v2, 0);  CSWAP_REG(v1, v3, 64);  }         \
        else if (j == 64) { CSWAP_REG(v0, v1, 0);  CSWAP_REG(v2, v3, 128); }         \
        else { CSWAP_SHFL(v0, 0); CSWAP_SHFL(v1, 64); CSWAP_SHFL(v2, 128); CSWAP_SHFL(v3, 192); } } }

  LOADV;
  for (int k = 2; k <= 256; k <<= 1) { LOCALPHASES(k >> 1); }
  STOREV;
  __syncthreads();

  for (int k = 512; k <= NBOX; k <<= 1) {
    for (int j = k >> 1; j >= 256; j >>= 1) {
      for (int i = tid; i < NBOX; i += NTHR) {
        int l = i ^ j;
        if (l > i) {
          ull a = sm.skey[i], c = sm.skey[l];
          if (((i & k) == 0) ? (a < c) : (a > c)) { sm.skey[i] = c; sm.skey[l] = a; }
        }
      }
      __syncthreads();
    }
    LOADV;
    LOCALPHASES(128);
    STOREV;
    __syncthreads();
  }

  int* wsb = ws_sorted + (size_t)b * N;
  int vc = (int)((v0 >> 32) != 0) + (int)((v1 >> 32) != 0)
         + (int)((v2 >> 32) != 0) + (int)((v3 >> 32) != 0);
  atomicAdd(&sm.vcount, vc);

  // fused prep: gather clipped + class-offset boxes and areas in sorted order
  float fimg = getimg(img_i);
  float offs = fimg + 1.0f;
  const float4* bx4 = (const float4*)(boxes + (size_t)b * N * 4);
  float4* obx = obox + (size_t)b * NBOX;
  float*  oar = area + (size_t)b * NBOX;
  #define EMIT(vm, mo) {                                                   \
      int idx = wbase + (mo) + lane;                                       \
      unsigned orig = 0xFFFFFFFFu - (unsigned)((vm) & 0xFFFFFFFFull);      \
      wsb[idx] = (int)orig;                                                \
      float4 bb = bx4[orig];                                               \
      float off = (float)lb[orig] * offs;                                  \
      bb.x = clipf(bb.x, fimg) + off;                                      \
      bb.y = clipf(bb.y, fimg) + off;                                      \
      bb.z = clipf(bb.z, fimg) + off;                                      \
      bb.w = clipf(bb.w, fimg) + off;                                      \
      obx[idx] = bb;                                                       \
      oar[idx] = fmaxf(bb.z - bb.x, 0.0f) * fmaxf(bb.w - bb.y, 0.0f);      \
  }
  EMIT(v0, 0); EMIT(v1, 64); EMIT(v2, 128); EMIT(v3, 192);

  __syncthreads();
  if (tid == 0) ws_V[b] = sm.vcount;
}

// =================== kernel T: TRANSPOSED suppression matrix chunk ===================
// trans[b][w][j] : bit r = cond(i = w*64+r, j)  (cond includes j > i)
// chunk c covers col-tiles jt in [jt0, jt0+16), word-groups wg in [0, c+1)
__global__ __launch_bounds__(256)
void suptr_chunk(const float4* __restrict__ obox,
                 const float*  __restrict__ area,
                 const float*  __restrict__ nms_th,
                 const int*    __restrict__ ws_V,
                 const int*    __restrict__ ws_done,
                 ull* __restrict__ trans,
                 int jt0)
{
  __shared__ float4 rbox[1024];
  __shared__ float  rarea[1024];

  const int b = blockIdx.y;
  if (ws_done[b]) return;
  const int jt = jt0 + (blockIdx.x & 15);
  const int wg = blockIdx.x >> 4;
  const int V  = ws_V[b];
  const int JW = (V + 63) >> 6;
  if (jt * 64 >= V) return;
  int w0 = wg * 16;
  int w1 = w0 + 16;
  if (w1 > jt + 1) w1 = jt + 1;
  if (w1 > JW)     w1 = JW;
  if (w0 >= w1) return;

  const int tid  = threadIdx.x;
  const int wave = tid >> 6;
  const int lane = tid & 63;

  double xt = (double)(*nms_th);
  float  th = (float)(1.0 / (1.0 + exp(-xt)));

  const float4* ob = obox + (size_t)b * NBOX;
  const float*  ar = area + (size_t)b * NBOX;

  const int nr = (w1 - w0) * 64;
  for (int e = tid; e < nr; e += 256) {
    rbox[e]  = ob[w0 * 64 + e];
    rarea[e] = ar[w0 * 64 + e];
  }
  __syncthreads();

  const int j  = jt * 64 + lane;
  const float4 bj = ob[j];
  const float  aj = ar[j];
  ull* tb = trans + (size_t)b * 64 * NBOX;

  for (int w = w0 + wave; w < w1; w += 4) {
    ull part = 0;
    const int rb = (w - w0) * 64;
    for (int rr = 0; rr < 64; ++rr) {
      const int i = w * 64 + rr;
      const float4 bi = rbox[rb + rr];
      const float  ai = rarea[rb + rr];
      float xx1 = fmaxf(bi.x, bj.x);
      float yy1 = fmaxf(bi.y, bj.y);
      float xx2 = fminf(bi.z, bj.z);
      float yy2 = fminf(bi.w, bj.w);
      float inter = fmaxf(xx2 - xx1, 0.0f) * fmaxf(yy2 - yy1, 0.0f);
      float denom = ai + aj;           // ((areas[i]+areas[j]) - inter) + 1e-9, ref order
      denom = denom - inter;
      denom = denom + 1e-9f;
      float iou = inter / denom;
      bool cond = (iou > th) && (j > i);
      part |= cond ? (1ull << rr) : 0ull;
    }
    tb[(size_t)w * NBOX + j] = part;   // coalesced across lanes
  }
}

// =================== kernel J: parallel Jacobi-fixpoint greedy resolve ===================
// Chunk over boxes [t0*64, t1*64), thread = box. Fixpoint of
//   a(j) = valid(j) & !catch(j) & !(exists i in-chunk: a(i) & sup(i,j))
// equals exact greedy (unique fixpoint on the prefix DAG).
__global__ __launch_bounds__(NTHR)
void resolve_jac(const int* __restrict__ ws_V,
                 const ull* __restrict__ trans,
                 int* __restrict__ ws_done,
                 int* __restrict__ ws_total,
                 ull* __restrict__ ws_keptw,
                 int* __restrict__ ws_kept,
                 int* __restrict__ ws_K,
                 int t0, int t1)
{
  __shared__ ull aw[16];    // alive words for this chunk
  __shared__ ull kw[64];    // kept bitmap (prior chunks + finalized current)
  __shared__ int flag, fin, Ktot;

  const int b = blockIdx.x;
  if (ws_done[b]) return;
  const int tid  = threadIdx.x;
  const int wave = tid >> 6;
  const int lane = tid & 63;
  const int V  = ws_V[b];
  const int JW = (V + 63) >> 6;
  const int j  = t0 * 64 + tid;
  const ull* tb = trans + (size_t)b * 64 * NBOX;
  ull* kwg = ws_keptw + (size_t)b * 64;
  const int total_in = (t0 == 0) ? 0 : ws_total[b];

  if (tid < 64) kw[tid] = (t0 > 0 && tid < t0) ? kwg[tid] : 0ull;

  // per-thread suppressed-by masks for in-chunk words (only w <= own word is defined)
  ull supT[16];
  #pragma unroll
  for (int w = 0; w < 16; ++w)
    supT[w] = (w <= wave) ? tb[(size_t)(t0 + w) * NBOX + j] : 0ull;
  __syncthreads();

  // catch-up: suppression by finalized prior kept
  ull cat = 0;
  for (int w = 0; w < t0; ++w) cat |= kw[w] & tb[(size_t)w * NBOX + j];
  const bool a0 = (j < V) && (cat == 0ull);
  {
    ull bw0 = __ballot(a0);
    if (lane == 0) aw[wave] = bw0;
  }
  __syncthreads();

  // Jacobi to fixpoint
  for (;;) {
    ull s = 0;
    #pragma unroll
    for (int w = 0; w < 16; ++w) s |= aw[w] & supT[w];
    const bool keep = a0 && (s == 0ull);
    const ull bw = __ballot(keep);
    const bool diff = (lane == 0) && (bw != aw[wave]);
    __syncthreads();
    if (tid == 0) flag = 0;
    __syncthreads();
    if (diff) { aw[wave] = bw; flag = 1; }
    __syncthreads();
    if (!flag) break;
  }

  // counts, trim to MAXDET, persist kept bitmap (wave 0)
  if (wave == 0) {
    ull w64 = (lane < 16) ? aw[lane] : 0ull;
    int pc = __popcll(w64);
    int incl = pc;
    #pragma unroll
    for (int s2 = 1; s2 < 64; s2 <<= 1) {
      int v = __shfl_up(incl, s2);
      if (lane >= s2) incl += v;
    }
    const int totalALL = total_in + __shfl(incl, 63);
    const bool fi = (totalALL >= MAXDET) || (t1 >= JW);
    if (fi) {
      int cumprev = total_in + incl - pc;
      int room = MAXDET - cumprev; if (room < 0) room = 0;
      int nk = (room < pc) ? room : pc;
      if (nk == 0) { w64 = 0; pc = 0; }
      else while (pc > nk) {
        int msb = 63 - __builtin_clzll(w64);
        w64 &= ~(1ull << msb);
        --pc;
      }
      if (lane < 16) { kwg[t0 + lane] = w64; kw[t0 + lane] = w64; }
    } else {
      if (lane < 16) kwg[t0 + lane] = w64;
    }
    if (lane == 0) {
      fin  = fi ? 1 : 0;
      Ktot = (totalALL < MAXDET) ? totalALL : MAXDET;
    }
  }
  __syncthreads();

  if (!fin) {
    if (tid == 0) ws_total[b] = Ktot;
    return;
  }

  // expand kept bitmap -> ordered kept list (wave 0, 64 words)
  if (wave == 0) {
    ull km = kw[lane];
    int pc = __popcll(km);
    int incl = pc;
    #pragma unroll
    for (int s2 = 1; s2 < 64; s2 <<= 1) {
      int v = __shfl_up(incl, s2);
      if (lane >= s2) incl += v;
    }
    int base = incl - pc;
    int* kg = ws_kept + (size_t)b * MAXDET;
    while (km) {
      int l = __builtin_ctzll(km);
      km &= km - 1;
      kg[base++] = lane * 64 + l;
    }
  }
  if (tid == 0) { ws_K[b] = Ktot; ws_done[b] = 1; }
}

// =================== kernel O: gather + write outputs ===================
__global__ __launch_bounds__(256)
void write_out(const float* __restrict__ boxes,
               const float* __restrict__ scores,
               const int*   __restrict__ labels,
               const int*   __restrict__ img_i,
               float* __restrict__ out,
               int B, int N,
               const int* __restrict__ ws_sorted,
               const int* __restrict__ ws_K,
               const int* __restrict__ ws_kept)
{
  const int b   = blockIdx.x;
  const int tid = threadIdx.x;
  const int K   = ws_K[b];
  const int* kg = ws_kept + (size_t)b * MAXDET;

  float fimg = getimg(img_i);
  const float* bx = boxes  + (size_t)b * N * 4;
  const float* sc = scores + (size_t)b * N;
  const int*   lb = labels + (size_t)b * N;
  const int*   so = ws_sorted + (size_t)b * N;

  float4* obx = (float4*)out;
  float*  osc = out + (size_t)B * MAXDET * 4;
  float*  olb = osc + (size_t)B * MAXDET;
  float*  ovl = olb + (size_t)B * MAXDET;
  for (int rI = tid; rI < MAXDET; rI += 256) {
    size_t slot = (size_t)b * MAXDET + rI;
    if (rI < K) {
      int i    = kg[rI];
      int orig = so[i];
      float4 bb = ((const float4*)bx)[orig];
      bb.x = clipf(bb.x, fimg);
      bb.y = clipf(bb.y, fimg);
      bb.z = clipf(bb.z, fimg);
      bb.w = clipf(bb.w, fimg);
      obx[slot] = bb;
      osc[slot] = sc[orig];
      olb[slot] = (float)lb[orig];
      ovl[slot] = 1.0f;
    } else {
      obx[slot] = make_float4(0.f, 0.f, 0.f, 0.f);
      osc[slot] = 0.0f;
      olb[slot] = 0.0f;
      ovl[slot] = 0.0f;
    }
  }
}

// =================== fallback kernel (round-2 path, used if ws too small) ===================
struct SMB {
  float4       obox[CAP];
  unsigned int keepw[NWORDS];
  int          kept_pos[MAXDET];
  int          scal[4];
};

__global__ __launch_bounds__(NTHR)
void nms_kernel(const float* __restrict__ boxes,
                const float* __restrict__ scores,
                const int*   __restrict__ labels,
                const float* __restrict__ nms_th,
                const float* __restrict__ cls_w,
                const int*   __restrict__ img_i,
                float* __restrict__ out,
                int B, int N,
                const int* __restrict__ ws_sorted,
                const int* __restrict__ ws_V,
                float4* __restrict__ ws_ovf)
{
  __shared__ SMB sm;
  const int b    = blockIdx.x;
  const int tid  = threadIdx.x;

  const float* bx = boxes  + (size_t)b * N * 4;
  const float* sc = scores + (size_t)b * N;
  const int*   lb = labels + (size_t)b * N;
  const int*   so = ws_sorted + (size_t)b * N;

  float fimg = getimg(img_i);
  float off_scale = fimg + 1.0f;
  double xt = (double)(*nms_th);
  float  th = (float)(1.0 / (1.0 + exp(-xt)));

  const int V = ws_V[b];
  if (tid < 4) sm.scal[tid] = 0;

  for (int m = 0; m < 4; ++m) {
    int i = tid + m * NTHR;
    int orig = so[i];
    float4 bb = ((const float4*)bx)[orig];
    float off = (float)lb[orig] * off_scale;
    bb.x = clipf(bb.x, fimg) + off;
    bb.y = clipf(bb.y, fimg) + off;
    bb.z = clipf(bb.z, fimg) + off;
    bb.w = clipf(bb.w, fimg) + off;
    if (i < CAP) sm.obox[i] = bb;
    else         ws_ovf[(size_t)b * (NBOX - CAP) + (i - CAP)] = bb;
  }
  for (int w = tid; w < NWORDS; w += NTHR) {
    int lo = w * 32;
    unsigned val;
    if      (V >= lo + 32) val = 0xFFFFFFFFu;
    else if (V <= lo)      val = 0u;
    else                   val = (1u << (V - lo)) - 1u;
    sm.keepw[w] = val;
  }
  __syncthreads();

  const int nt = (V + 63) >> 6;
  int TR = 0;
  for (int t = 0; t < nt; ++t) {
    if (tid < 64) {
      int i0 = t * 64;
      int me = i0 + tid;
      float4 bb = (me < CAP) ? sm.obox[me]
                             : ws_ovf[(size_t)b * (NBOX - CAP) + (me - CAP)];
      float arJ = fmaxf(bb.z - bb.x, 0.0f) * fmaxf(bb.w - bb.y, 0.0f);
      ull supby = 0;
      for (int l = 0; l < 64; ++l) {
        int i = i0 + l;
        float4 bi = (i < CAP) ? sm.obox[i]
                              : ws_ovf[(size_t)b * (NBOX - CAP) + (i - CAP)];
        float ai = fmaxf(bi.z - bi.x, 0.0f) * fmaxf(bi.w - bi.y, 0.0f);
        float xx1 = fmaxf(bi.x, bb.x);
        float yy1 = fmaxf(bi.y, bb.y);
        float xx2 = fminf(bi.z, bb.z);
        float yy2 = fminf(bi.w, bb.w);
        float inter = fmaxf(xx2 - xx1, 0.0f) * fmaxf(yy2 - yy1, 0.0f);
        float denom = ai + arJ;
        denom = denom - inter;
        denom = denom + 1e-9f;
        float iou = inter / denom;
        if (iou > th) supby |= (1ull << l);
      }
      ull alive = ((ull)sm.keepw[2 * t + 1] << 32) | sm.keepw[2 * t];
      ull rem = alive;
      while (rem) {
        int l = __builtin_ctzll(rem);
        rem &= rem - 1;
        ull sup = __ballot((supby >> l) & 1ull);
        sup &= ((~1ull) << l);
        sup &= alive;
        alive &= ~sup;
        rem   &= ~sup;
      }
      if (tid == 0) {
        sm.keepw[2 * t]     = (unsigned)alive;
        sm.keepw[2 * t + 1] = (unsigned)(alive >> 32);
        atomicAdd(&sm.scal[1], __builtin_popcountll(alive));
      }
    }
    __syncthreads();
    TR = t + 1;
    if (sm.scal[1] >= MAXDET) break;

    int jstart = (t + 1) * 64;
    if (jstart < V) {
      ull alive = ((ull)sm.keepw[2 * t + 1] << 32) | sm.keepw[2 * t];
      if (alive) {
        for (int j = jstart + tid; j < V; j += NTHR) {
          unsigned wj = sm.keepw[j >> 5];
          if (!((wj >> (j & 31)) & 1u)) continue;
          float4 bj = (j < CAP) ? sm.obox[j]
                                : ws_ovf[(size_t)b * (NBOX - CAP) + (j - CAP)];
          float aj = fmaxf(bj.z - bj.x, 0.0f) * fmaxf(bj.w - bj.y, 0.0f);
          ull rem = alive;
          bool suppressed = false;
          while (rem) {
            int l = __builtin_ctzll(rem);
            rem &= rem - 1;
            int i = t * 64 + l;
            float4 bi = (i < CAP) ? sm.obox[i]
                                  : ws_ovf[(size_t)b * (NBOX - CAP) + (i - CAP)];
            float ai = fmaxf(bi.z - bi.x, 0.0f) * fmaxf(bi.w - bi.y, 0.0f);
            float xx1 = fmaxf(bi.x, bj.x);
            float yy1 = fmaxf(bi.y, bj.y);
            float xx2 = fminf(bi.z, bj.z);
            float yy2 = fminf(bi.w, bj.w);
            float inter = fmaxf(xx2 - xx1, 0.0f) * fmaxf(yy2 - yy1, 0.0f);
            float denom = ai + aj;
            denom = denom - inter;
            denom = denom + 1e-9f;
            float iou = inter / denom;
            if (iou > th) { suppressed = true; break; }
          }
          if (suppressed) atomicAnd(&sm.keepw[j >> 5], ~(1u << (j & 31)));
        }
      }
    }
    __syncthreads();
  }

  if (tid < NWORDS && tid >= TR * 2) sm.keepw[tid] = 0;
  __syncthreads();
  if (tid == 0) {
    int r = 0;
    for (int w = 0; w < NWORDS && r < MAXDET; ++w) {
      unsigned bits = sm.keepw[w];
      while (bits && r < MAXDET) {
        int l = __builtin_ctz(bits);
        bits &= bits - 1;
        sm.kept_pos[r++] = w * 32 + l;
      }
    }
    sm.scal[3] = r;
  }
  __syncthreads();
  const int K = sm.scal[3];

  float4* obx = (float4*)out;
  float*  osc = out + (size_t)B * MAXDET * 4;
  float*  olb = osc + (size_t)B * MAXDET;
  float*  ovl = olb + (size_t)B * MAXDET;
  for (int r = tid; r < MAXDET; r += NTHR) {
    size_t slot = (size_t)b * MAXDET + r;
    if (r < K) {
      int i    = sm.kept_pos[r];
      int orig = so[i];
      float4 bb = ((const float4*)bx)[orig];
      bb.x = clipf(bb.x, fimg);
      bb.y = clipf(bb.y, fimg);
      bb.z = clipf(bb.z, fimg);
      bb.w = clipf(bb.w, fimg);
      obx[slot] = bb;
      osc[slot] = sc[orig];
      olb[slot] = (float)lb[orig];
      ovl[slot] = 1.0f;
    } else {
      obx[slot] = make_float4(0.f, 0.f, 0.f, 0.f);
      osc[slot] = 0.0f;
      olb[slot] = 0.0f;
      ovl[slot] = 0.0f;
    }
  }
}

extern "C" void kernel_launch(void* const* d_in, const int* in_sizes, int n_in,
                              void* d_out, int out_size, void* d_ws, size_t ws_size,
                              hipStream_t stream) {
  const float* boxes      = (const float*)d_in[0];
  const float* scores     = (const float*)d_in[1];
  const int*   labels     = (const int*)d_in[2];
  const float* nms_thresh = (const float*)d_in[3];
  const float* cls_w      = (const float*)d_in[4];
  const int*   img_sz     = (const int*)d_in[5];

  int B = out_size / (MAXDET * 7);
  int N = in_sizes[1] / B;               // 4096

  // ws layout
  size_t sz_sorted = (size_t)B * N * 4;
  size_t off_V     = sz_sorted;
  size_t off_obox  = sz_sorted + 1024;
  size_t sz_obox   = (size_t)B * NBOX * 16;
  size_t off_area  = off_obox + sz_obox;
  size_t sz_area   = (size_t)B * NBOX * 4;
  size_t off_done  = (off_area + sz_area + 255) & ~(size_t)255;
  size_t off_total = off_done + (size_t)B * 4;
  size_t off_Kf    = off_total + (size_t)B * 4;
  size_t off_kept  = off_Kf + (size_t)B * 4;
  size_t off_kw    = (off_kept + (size_t)B * MAXDET * 4 + 255) & ~(size_t)255;
  size_t sz_kw     = (size_t)B * 64 * 8;            // kept bitmaps
  size_t off_tr    = (off_kw + sz_kw + 255) & ~(size_t)255;
  size_t sz_tr     = (size_t)B * 64 * NBOX * 8;     // 32 MiB transposed supmat
  size_t need_fast = off_tr + sz_tr;

  int*    ws_sorted = (int*)d_ws;
  int*    ws_V      = (int*)((char*)d_ws + off_V);
  int*    ws_done   = (int*)((char*)d_ws + off_done);
  float4* obox      = (float4*)((char*)d_ws + off_obox);
  float*  area      = (float*)((char*)d_ws + off_area);

  sort_kernel<<<dim3(B), dim3(NTHR), 0, stream>>>(
      scores, labels, cls_w, boxes, img_sz,
      ws_sorted, ws_V, ws_done, obox, area, N);

  if (ws_size >= need_fast && N == NBOX) {
    int* ws_total = (int*)((char*)d_ws + off_total);
    int* ws_K     = (int*)((char*)d_ws + off_Kf);
    int* ws_kept  = (int*)((char*)d_ws + off_kept);
    ull* ws_keptw = (ull*)((char*)d_ws + off_kw);
    ull* trans    = (ull*)((char*)d_ws + off_tr);

    for (int c = 0; c < 4; ++c) {
      suptr_chunk<<<dim3(16 * (c + 1), B), dim3(256), 0, stream>>>(
          obox, area, nms_thresh, ws_V, ws_done, trans, 16 * c);
      resolve_jac<<<dim3(B), dim3(NTHR), 0, stream>>>(
          ws_V, trans, ws_done, ws_total, ws_keptw, ws_kept, ws_K,
          16 * c, 16 * (c + 1));
    }

    write_out<<<dim3(B), dim3(256), 0, stream>>>(
        boxes, scores, labels, img_sz, (float*)d_out, B, N,
        ws_sorted, ws_K, ws_kept);
  } else {
    float4* ws_ovf = (float4*)((char*)d_ws + off_done + 1024);
    nms_kernel<<<dim3(B), dim3(NTHR), 0, stream>>>(boxes, scores, labels,
                                                   nms_thresh, cls_w, img_sz,
                                                   (float*)d_out, B, N,
                                                   ws_sorted, ws_V, ws_ovf);
  }
}

// Round 13
// 75.760 us; speedup vs baseline: 2.9221x; 1.3124x over previous
//
#include <hip/hip_runtime.h>
#include <math.h>

#define NBOX   4096
#define NTHR   1024
#define MAXDET 300
#define CAP    3968          // fallback path
#define NWORDS (NBOX / 32)

typedef unsigned long long ull;

__device__ __forceinline__ float clipf(float v, float hi) {
  return fminf(fmaxf(v, 0.0f), hi);
}

__device__ __forceinline__ float getimg(const int* img_i) {
  int iv = *img_i;
  return (iv > 0 && iv < (1 << 24)) ? (float)iv : __int_as_float(iv);
}

// comparator macros: "up" (e&K)==0 => descending run (matches argsort(-key))
#define CSWAP_REG(va, vb, eo, K) { int e_ = wbase + (eo) + lane;                     \
    if ((((e_) & (K)) == 0) ? ((va) < (vb)) : ((va) > (vb))) { ull t_=(va); (va)=(vb); (vb)=t_; } }
#define CSWAP_SHFL(vr, eo, K) { int e_ = wbase + (eo) + lane;                        \
    ull c_ = __shfl_xor((vr), j);                                                    \
    bool km_ = ((((e_) & (K)) == 0) == ((lane & j) == 0));                           \
    (vr) = km_ ? ((vr) > c_ ? (vr) : c_) : ((vr) < c_ ? (vr) : c_); }
#define LOCALPHASES(jmax, K) { for (int j = (jmax); j >= 1; j >>= 1) {               \
    if (j == 128)      { CSWAP_REG(v0, v2, 0, K);  CSWAP_REG(v1, v3, 64, K);  }      \
    else if (j == 64)  { CSWAP_REG(v0, v1, 0, K);  CSWAP_REG(v2, v3, 128, K); }      \
    else { CSWAP_SHFL(v0, 0, K); CSWAP_SHFL(v1, 64, K); CSWAP_SHFL(v2, 128, K); CSWAP_SHFL(v3, 192, K); } } }

__device__ __forceinline__ void emit_one(ull key, int l, int b, int N,
    const float* boxes, const int* labels, float fimg, float offs,
    int* ws_sorted, float4* obox, float* area)
{
  unsigned orig = 0xFFFFFFFFu - (unsigned)(key & 0xFFFFFFFFull);
  ws_sorted[(size_t)b * N + l] = (int)orig;
  const float4* bx4 = (const float4*)(boxes + (size_t)b * N * 4);
  float4 bb = bx4[orig];
  float off = (float)labels[(size_t)b * N + orig] * offs;
  bb.x = clipf(bb.x, fimg) + off;
  bb.y = clipf(bb.y, fimg) + off;
  bb.z = clipf(bb.z, fimg) + off;
  bb.w = clipf(bb.w, fimg) + off;
  obox[(size_t)b * NBOX + l] = bb;
  area[(size_t)b * NBOX + l] = fmaxf(bb.z - bb.x, 0.0f) * fmaxf(bb.w - bb.y, 0.0f);
}

// =================== S1: per-1024-segment key build + bitonic sort (descending) ===================
__global__ __launch_bounds__(256)
void sort_seg(const float* __restrict__ scores,
              const int*   __restrict__ labels,
              const float* __restrict__ cls_w,
              ull* __restrict__ ws_keys,
              int* __restrict__ ws_Vseg,
              int N)
{
  __shared__ ull ks[1024];
  __shared__ int cnt;
  const int b = blockIdx.y, s = blockIdx.x;
  const int tid = threadIdx.x, lane = tid & 63, wave = tid >> 6;
  const int wbase = wave * 256;
  const int base  = s * 1024;
  const float* sc = scores + (size_t)b * N;
  const int*   lb = labels + (size_t)b * N;
  if (tid == 0) cnt = 0;

  ull v0, v1, v2, v3;
  int vc = 0;
  #define BUILD(vm, mo) { int l_ = wbase + (mo) + lane; int gi = base + l_;          \
      float sv = sc[gi]; ull key = (ull)(0xFFFFFFFFu - (unsigned)gi);                \
      if (sv > 0.3f) { float w_ = sv * cls_w[lb[gi]]; unsigned ub = __float_as_uint(w_); \
        ub = (ub & 0x80000000u) ? ~ub : (ub | 0x80000000u);                          \
        key |= ((ull)ub << 32); ++vc; }                                              \
      vm = key; }
  BUILD(v0, 0) BUILD(v1, 64) BUILD(v2, 128) BUILD(v3, 192)
  #undef BUILD
  atomicAdd(&cnt, vc);

  // stages k=2..256: wave-local (directions from local element index)
  for (int k2 = 2; k2 <= 256; k2 <<= 1) { LOCALPHASES(k2 >> 1, k2); }

  #define STV { ks[wbase + lane] = v0; ks[wbase + 64 + lane] = v1;                   \
                ks[wbase + 128 + lane] = v2; ks[wbase + 192 + lane] = v3; }
  #define LDV { v0 = ks[wbase + lane]; v1 = ks[wbase + 64 + lane];                   \
                v2 = ks[wbase + 128 + lane]; v3 = ks[wbase + 192 + lane]; }
  #define CROSS(J, K) { for (int i = tid; i < 1024; i += 256) { int l2 = i ^ (J);    \
      if (l2 > i) { ull a = ks[i], c = ks[l2];                                       \
        if ((((i) & (K)) == 0) ? (a < c) : (a > c)) { ks[i] = c; ks[l2] = a; } } } }

  STV; __syncthreads();
  CROSS(256, 512); __syncthreads();
  LDV; LOCALPHASES(128, 512);
  STV; __syncthreads();
  CROSS(512, 1024); __syncthreads();
  CROSS(256, 1024); __syncthreads();
  LDV; LOCALPHASES(128, 1024);

  // write sorted segment (descending) to global keys
  ull* kb = ws_keys + (size_t)b * NBOX + base;
  kb[wbase + lane]       = v0;
  kb[wbase + 64 + lane]  = v1;
  kb[wbase + 128 + lane] = v2;
  kb[wbase + 192 + lane] = v3;
  __syncthreads();
  if (tid == 0) ws_Vseg[b * 4 + s] = cnt;
  #undef STV
  #undef LDV
  #undef CROSS
}

// =================== M: tournament top-1024 merge + fused prep (ranks 0..1023) ===================
__global__ __launch_bounds__(512)
void merge_top(const ull* __restrict__ ws_keys,
               const int* __restrict__ ws_Vseg,
               const float* __restrict__ boxes,
               const int*   __restrict__ labels,
               const int*   __restrict__ img_i,
               int*    __restrict__ ws_sorted,
               int*    __restrict__ ws_V,
               int*    __restrict__ ws_done,
               float4* __restrict__ obox,
               float*  __restrict__ area,
               int N)
{
  __shared__ ull ksh[2][1024];
  const int b = blockIdx.x;
  const int tid = threadIdx.x, lane = tid & 63, wave = tid >> 6;
  const int g = wave >> 2, wv = wave & 3;
  const int wbase = wv * 256;
  const ull* kb = ws_keys + (size_t)b * NBOX;

  ull v0, v1, v2, v3;
  // half-cleaner of (seg2g, seg2g+1): elementwise max(A[l], B[1023-l]) = top-1024, bitonic
  #define PMAX(vm, mo) { int l_ = wbase + (mo) + lane;                               \
      ull a = kb[g * 2048 + l_]; ull c = kb[g * 2048 + 1024 + (1023 - l_)];          \
      vm = (a > c) ? a : c; }
  PMAX(v0, 0) PMAX(v1, 64) PMAX(v2, 128) PMAX(v3, 192)
  #undef PMAX

  #define STVG(arr) { (arr)[wbase + lane] = v0; (arr)[wbase + 64 + lane] = v1;       \
                      (arr)[wbase + 128 + lane] = v2; (arr)[wbase + 192 + lane] = v3; }
  #define LDVG(arr) { v0 = (arr)[wbase + lane]; v1 = (arr)[wbase + 64 + lane];       \
                      v2 = (arr)[wbase + 128 + lane]; v3 = (arr)[wbase + 192 + lane]; }
  #define MCROSS(arr, J) { for (int i = (tid & 255); i < 1024; i += 256) {           \
      int l2 = i ^ (J); if (l2 > i) { ull a = (arr)[i], c = (arr)[l2];               \
        if (a < c) { (arr)[i] = c; (arr)[l2] = a; } } } }

  // clean each group's bitonic 1024 -> sorted descending
  STVG(ksh[g]); __syncthreads();
  MCROSS(ksh[g], 512); __syncthreads();
  MCROSS(ksh[g], 256); __syncthreads();
  LDVG(ksh[g]); LOCALPHASES(128, 2048);   // K=2048 -> up everywhere (pure clean)
  STVG(ksh[g]); __syncthreads();

  // final: top-1024 of (t01, t23)
  if (g == 0) {
    #define PMAX2(vm, mo) { int l_ = wbase + (mo) + lane;                            \
        ull a = ksh[0][l_]; ull c = ksh[1][1023 - l_]; vm = (a > c) ? a : c; }
    PMAX2(v0, 0) PMAX2(v1, 64) PMAX2(v2, 128) PMAX2(v3, 192)
    #undef PMAX2
  }
  __syncthreads();
  if (g == 0) STVG(ksh[0]);
  __syncthreads();
  if (tid < 256) MCROSS(ksh[0], 512);
  __syncthreads();
  if (tid < 256) MCROSS(ksh[0], 256);
  __syncthreads();

  if (g == 0) {
    LDVG(ksh[0]); LOCALPHASES(128, 2048);
    float fimg = getimg(img_i);
    float offs = fimg + 1.0f;
    emit_one(v0, wbase + lane,       b, N, boxes, labels, fimg, offs, ws_sorted, obox, area);
    emit_one(v1, wbase + 64 + lane,  b, N, boxes, labels, fimg, offs, ws_sorted, obox, area);
    emit_one(v2, wbase + 128 + lane, b, N, boxes, labels, fimg, offs, ws_sorted, obox, area);
    emit_one(v3, wbase + 192 + lane, b, N, boxes, labels, fimg, offs, ws_sorted, obox, area);
  }
  if (tid == 0) {
    ws_V[b] = ws_Vseg[b * 4] + ws_Vseg[b * 4 + 1] + ws_Vseg[b * 4 + 2] + ws_Vseg[b * 4 + 3];
    ws_done[b] = 0;
  }
  #undef STVG
  #undef LDVG
  #undef MCROSS
}

// =================== R1: full 4-way merge (rare path; gated) -> ranks 1024..4095 ===================
__global__ __launch_bounds__(NTHR)
void merge_full(const ull* __restrict__ ws_keys,
                const int* __restrict__ ws_done,
                const float* __restrict__ boxes,
                const int*   __restrict__ labels,
                const int*   __restrict__ img_i,
                int*    __restrict__ ws_sorted,
                float4* __restrict__ obox,
                float*  __restrict__ area,
                int N)
{
  __shared__ ull K[4096];
  const int b = blockIdx.x;
  if (ws_done[b]) return;
  const int tid = threadIdx.x;
  const ull* kb = ws_keys + (size_t)b * NBOX;
  for (int i = tid; i < 4096; i += NTHR) K[i] = kb[i];
  __syncthreads();

  // merge (seg0,seg1) and (seg2,seg3): half-cleaners
  {
    int i = tid;                   // 0..1023
    { ull a = K[i], c = K[2047 - i];            if (a < c) { K[i] = c; K[2047 - i] = a; } }
    { ull a = K[2048 + i], c = K[4095 - i];     if (a < c) { K[2048 + i] = c; K[4095 - i] = a; } }
  }
  __syncthreads();
  for (int j = 512; j >= 1; j >>= 1) {          // clean all four 1024-halves (descending)
    for (int idx = tid; idx < 4096; idx += NTHR) {
      int l = idx ^ j;
      if (l > idx) { ull a = K[idx], c = K[l]; if (a < c) { K[idx] = c; K[l] = a; } }
    }
    __syncthreads();
  }
  // final half-cleaner of (D01, D23)
  for (int m = 0; m < 2; ++m) {
    int i2 = tid + m * 1024;       // 0..2047
    ull a = K[i2], c = K[4095 - i2];
    if (a < c) { K[i2] = c; K[4095 - i2] = a; }
  }
  __syncthreads();
  for (int j = 1024; j >= 1; j >>= 1) {         // clean both 2048-halves
    for (int idx = tid; idx < 4096; idx += NTHR) {
      int l = idx ^ j;
      if (l > idx) { ull a = K[idx], c = K[l]; if (a < c) { K[idx] = c; K[l] = a; } }
    }
    __syncthreads();
  }

  float fimg = getimg(img_i);
  float offs = fimg + 1.0f;
  for (int idx = 1024 + tid; idx < 4096; idx += NTHR)
    emit_one(K[idx], idx, b, N, boxes, labels, fimg, offs, ws_sorted, obox, area);
}

// =================== T: transposed suppression matrix, block per (word, col-tile) ===================
// trans[b][w][j] : bit r = cond(i = w*64+r, j); chunk covers jt in [jt0, jt0+16)
__global__ __launch_bounds__(256)
void suptr_chunk(const float4* __restrict__ obox,
                 const float*  __restrict__ area,
                 const float*  __restrict__ nms_th,
                 const int*    __restrict__ ws_V,
                 const int*    __restrict__ ws_done,
                 ull* __restrict__ trans,
                 int jt0)
{
  __shared__ float4 rbox[64];
  __shared__ float  rarea[64];
  __shared__ ull    part[4][64];
  const int b = blockIdx.y;
  if (ws_done[b]) return;
  int rem = blockIdx.x, d = 0;
  while (rem >= jt0 + d + 1) { rem -= jt0 + d + 1; ++d; }
  const int jt = jt0 + d, w = rem;
  const int V = ws_V[b];
  if (jt * 64 >= V) return;
  const int JW = (V + 63) >> 6;
  if (w >= JW) return;

  const int tid = threadIdx.x, wave = tid >> 6, lane = tid & 63;
  double xt = (double)(*nms_th);
  float  th = (float)(1.0 / (1.0 + exp(-xt)));
  const float4* ob = obox + (size_t)b * NBOX;
  const float*  ar = area + (size_t)b * NBOX;

  if (tid < 64) { rbox[tid] = ob[w * 64 + tid]; rarea[tid] = ar[w * 64 + tid]; }
  __syncthreads();

  const int j = jt * 64 + lane;
  const float4 bj = ob[j];
  const float  aj = ar[j];
  ull p = 0;
  #pragma unroll 4
  for (int rr = 0; rr < 16; ++rr) {
    const int r = wave * 16 + rr;
    const int i = w * 64 + r;
    const float4 bi = rbox[r];
    const float  ai = rarea[r];
    float xx1 = fmaxf(bi.x, bj.x);
    float yy1 = fmaxf(bi.y, bj.y);
    float xx2 = fminf(bi.z, bj.z);
    float yy2 = fminf(bi.w, bj.w);
    float inter = fmaxf(xx2 - xx1, 0.0f) * fmaxf(yy2 - yy1, 0.0f);
    float denom = ai + aj;           // ((areas[i]+areas[j]) - inter) + 1e-9, ref order
    denom = denom - inter;
    denom = denom + 1e-9f;
    float iou = inter / denom;
    bool cond = (iou > th) && (j > i);
    p |= cond ? (1ull << r) : 0ull;
  }
  part[wave][lane] = p;
  __syncthreads();
  if (tid < 64)
    trans[(size_t)b * 64 * NBOX + (size_t)w * NBOX + jt * 64 + tid] =
        (part[0][tid] | part[1][tid]) | (part[2][tid] | part[3][tid]);
}

// =================== J: parallel Jacobi-fixpoint greedy resolve (round-12, proven) ===================
__global__ __launch_bounds__(NTHR)
void resolve_jac(const int* __restrict__ ws_V,
                 const ull* __restrict__ trans,
                 int* __restrict__ ws_done,
                 int* __restrict__ ws_total,
                 ull* __restrict__ ws_keptw,
                 int* __restrict__ ws_kept,
                 int* __restrict__ ws_K,
                 int t0, int t1)
{
  __shared__ ull aw[16];
  __shared__ ull kw[64];
  __shared__ int flag, fin, Ktot;

  const int b = blockIdx.x;
  if (ws_done[b]) return;
  const int tid  = threadIdx.x;
  const int wave = tid >> 6;
  const int lane = tid & 63;
  const int V  = ws_V[b];
  const int JW = (V + 63) >> 6;
  const int j  = t0 * 64 + tid;
  const ull* tb = trans + (size_t)b * 64 * NBOX;
  ull* kwg = ws_keptw + (size_t)b * 64;
  const int total_in = (t0 == 0) ? 0 : ws_total[b];

  if (tid < 64) kw[tid] = (t0 > 0 && tid < t0) ? kwg[tid] : 0ull;

  ull supT[16];
  #pragma unroll
  for (int w = 0; w < 16; ++w)
    supT[w] = (w <= wave) ? tb[(size_t)(t0 + w) * NBOX + j] : 0ull;
  __syncthreads();

  ull cat = 0;
  for (int w = 0; w < t0; ++w) cat |= kw[w] & tb[(size_t)w * NBOX + j];
  const bool a0 = (j < V) && (cat == 0ull);
  {
    ull bw0 = __ballot(a0);
    if (lane == 0) aw[wave] = bw0;
  }
  __syncthreads();

  for (;;) {
    ull s = 0;
    #pragma unroll
    for (int w = 0; w < 16; ++w) s |= aw[w] & supT[w];
    const bool keep = a0 && (s == 0ull);
    const ull bw = __ballot(keep);
    const bool diff = (lane == 0) && (bw != aw[wave]);
    __syncthreads();
    if (tid == 0) flag = 0;
    __syncthreads();
    if (diff) { aw[wave] = bw; flag = 1; }
    __syncthreads();
    if (!flag) break;
  }

  if (wave == 0) {
    ull w64 = (lane < 16) ? aw[lane] : 0ull;
    int pc = __popcll(w64);
    int incl = pc;
    #pragma unroll
    for (int s2 = 1; s2 < 64; s2 <<= 1) {
      int v = __shfl_up(incl, s2);
      if (lane >= s2) incl += v;
    }
    const int totalALL = total_in + __shfl(incl, 63);
    const bool fi = (totalALL >= MAXDET) || (t1 >= JW);
    if (fi) {
      int cumprev = total_in + incl - pc;
      int room = MAXDET - cumprev; if (room < 0) room = 0;
      int nk = (room < pc) ? room : pc;
      if (nk == 0) { w64 = 0; pc = 0; }
      else while (pc > nk) {
        int msb = 63 - __builtin_clzll(w64);
        w64 &= ~(1ull << msb);
        --pc;
      }
      if (lane < 16) { kwg[t0 + lane] = w64; kw[t0 + lane] = w64; }
    } else {
      if (lane < 16) kwg[t0 + lane] = w64;
    }
    if (lane == 0) {
      fin  = fi ? 1 : 0;
      Ktot = (totalALL < MAXDET) ? totalALL : MAXDET;
    }
  }
  __syncthreads();

  if (!fin) {
    if (tid == 0) ws_total[b] = Ktot;
    return;
  }

  if (wave == 0) {
    ull km = kw[lane];
    int pc = __popcll(km);
    int incl = pc;
    #pragma unroll
    for (int s2 = 1; s2 < 64; s2 <<= 1) {
      int v = __shfl_up(incl, s2);
      if (lane >= s2) incl += v;
    }
    int base = incl - pc;
    int* kg = ws_kept + (size_t)b * MAXDET;
    while (km) {
      int l = __builtin_ctzll(km);
      km &= km - 1;
      kg[base++] = lane * 64 + l;
    }
  }
  if (tid == 0) { ws_K[b] = Ktot; ws_done[b] = 1; }
}

// =================== O: gather + write outputs ===================
__global__ __launch_bounds__(256)
void write_out(const float* __restrict__ boxes,
               const float* __restrict__ scores,
               const int*   __restrict__ labels,
               const int*   __restrict__ img_i,
               float* __restrict__ out,
               int B, int N,
               const int* __restrict__ ws_sorted,
               const int* __restrict__ ws_K,
               const int* __restrict__ ws_kept)
{
  const int b   = blockIdx.x;
  const int tid = threadIdx.x;
  const int K   = ws_K[b];
  const int* kg = ws_kept + (size_t)b * MAXDET;

  float fimg = getimg(img_i);
  const float* bx = boxes  + (size_t)b * N * 4;
  const float* sc = scores + (size_t)b * N;
  const int*   lb = labels + (size_t)b * N;
  const int*   so = ws_sorted + (size_t)b * N;

  float4* obx = (float4*)out;
  float*  osc = out + (size_t)B * MAXDET * 4;
  float*  olb = osc + (size_t)B * MAXDET;
  float*  ovl = olb + (size_t)B * MAXDET;
  for (int rI = tid; rI < MAXDET; rI += 256) {
    size_t slot = (size_t)b * MAXDET + rI;
    if (rI < K) {
      int i    = kg[rI];
      int orig = so[i];
      float4 bb = ((const float4*)bx)[orig];
      bb.x = clipf(bb.x, fimg);
      bb.y = clipf(bb.y, fimg);
      bb.z = clipf(bb.z, fimg);
      bb.w = clipf(bb.w, fimg);
      obx[slot] = bb;
      osc[slot] = sc[orig];
      olb[slot] = (float)lb[orig];
      ovl[slot] = 1.0f;
    } else {
      obx[slot] = make_float4(0.f, 0.f, 0.f, 0.f);
      osc[slot] = 0.0f;
      olb[slot] = 0.0f;
      ovl[slot] = 0.0f;
    }
  }
}

// =================== fallback kernel (round-2 path, used if ws too small) ===================
struct SMB {
  float4       obox[CAP];
  unsigned int keepw[NWORDS];
  int          kept_pos[MAXDET];
  int          scal[4];
};

__global__ __launch_bounds__(NTHR)
void nms_kernel(const float* __restrict__ boxes,
                const float* __restrict__ scores,
                const int*   __restrict__ labels,
                const float* __restrict__ nms_th,
                const float* __restrict__ cls_w,
                const int*   __restrict__ img_i,
                float* __restrict__ out,
                int B, int N,
                const int* __restrict__ ws_sorted,
                const int* __restrict__ ws_V,
                float4* __restrict__ ws_ovf)
{
  __shared__ SMB sm;
  const int b    = blockIdx.x;
  const int tid  = threadIdx.x;

  const float* bx = boxes  + (size_t)b * N * 4;
  const float* sc = scores + (size_t)b * N;
  const int*   lb = labels + (size_t)b * N;
  const int*   so = ws_sorted + (size_t)b * N;

  float fimg = getimg(img_i);
  float off_scale = fimg + 1.0f;
  double xt = (double)(*nms_th);
  float  th = (float)(1.0 / (1.0 + exp(-xt)));

  const int V = ws_V[b];
  if (tid < 4) sm.scal[tid] = 0;

  for (int m = 0; m < 4; ++m) {
    int i = tid + m * NTHR;
    int orig = so[i];
    float4 bb = ((const float4*)bx)[orig];
    float off = (float)lb[orig] * off_scale;
    bb.x = clipf(bb.x, fimg) + off;
    bb.y = clipf(bb.y, fimg) + off;
    bb.z = clipf(bb.z, fimg) + off;
    bb.w = clipf(bb.w, fimg) + off;
    if (i < CAP) sm.obox[i] = bb;
    else         ws_ovf[(size_t)b * (NBOX - CAP) + (i - CAP)] = bb;
  }
  for (int w = tid; w < NWORDS; w += NTHR) {
    int lo = w * 32;
    unsigned val;
    if      (V >= lo + 32) val = 0xFFFFFFFFu;
    else if (V <= lo)      val = 0u;
    else                   val = (1u << (V - lo)) - 1u;
    sm.keepw[w] = val;
  }
  __syncthreads();

  const int nt = (V + 63) >> 6;
  int TR = 0;
  for (int t = 0; t < nt; ++t) {
    if (tid < 64) {
      int i0 = t * 64;
      int me = i0 + tid;
      float4 bb = (me < CAP) ? sm.obox[me]
                             : ws_ovf[(size_t)b * (NBOX - CAP) + (me - CAP)];
      float arJ = fmaxf(bb.z - bb.x, 0.0f) * fmaxf(bb.w - bb.y, 0.0f);
      ull supby = 0;
      for (int l = 0; l < 64; ++l) {
        int i = i0 + l;
        float4 bi = (i < CAP) ? sm.obox[i]
                              : ws_ovf[(size_t)b * (NBOX - CAP) + (i - CAP)];
        float ai = fmaxf(bi.z - bi.x, 0.0f) * fmaxf(bi.w - bi.y, 0.0f);
        float xx1 = fmaxf(bi.x, bb.x);
        float yy1 = fmaxf(bi.y, bb.y);
        float xx2 = fminf(bi.z, bb.z);
        float yy2 = fminf(bi.w, bb.w);
        float inter = fmaxf(xx2 - xx1, 0.0f) * fmaxf(yy2 - yy1, 0.0f);
        float denom = ai + arJ;
        denom = denom - inter;
        denom = denom + 1e-9f;
        float iou = inter / denom;
        if (iou > th) supby |= (1ull << l);
      }
      ull alive = ((ull)sm.keepw[2 * t + 1] << 32) | sm.keepw[2 * t];
      ull rem = alive;
      while (rem) {
        int l = __builtin_ctzll(rem);
        rem &= rem - 1;
        ull sup = __ballot((supby >> l) & 1ull);
        sup &= ((~1ull) << l);
        sup &= alive;
        alive &= ~sup;
        rem   &= ~sup;
      }
      if (tid == 0) {
        sm.keepw[2 * t]     = (unsigned)alive;
        sm.keepw[2 * t + 1] = (unsigned)(alive >> 32);
        atomicAdd(&sm.scal[1], __builtin_popcountll(alive));
      }
    }
    __syncthreads();
    TR = t + 1;
    if (sm.scal[1] >= MAXDET) break;

    int jstart = (t + 1) * 64;
    if (jstart < V) {
      ull alive = ((ull)sm.keepw[2 * t + 1] << 32) | sm.keepw[2 * t];
      if (alive) {
        for (int j = jstart + tid; j < V; j += NTHR) {
          unsigned wj = sm.keepw[j >> 5];
          if (!((wj >> (j & 31)) & 1u)) continue;
          float4 bj = (j < CAP) ? sm.obox[j]
                                : ws_ovf[(size_t)b * (NBOX - CAP) + (j - CAP)];
          float aj = fmaxf(bj.z - bj.x, 0.0f) * fmaxf(bj.w - bj.y, 0.0f);
          ull rem = alive;
          bool suppressed = false;
          while (rem) {
            int l = __builtin_ctzll(rem);
            rem &= rem - 1;
            int i = t * 64 + l;
            float4 bi = (i < CAP) ? sm.obox[i]
                                  : ws_ovf[(size_t)b * (NBOX - CAP) + (i - CAP)];
            float ai = fmaxf(bi.z - bi.x, 0.0f) * fmaxf(bi.w - bi.y, 0.0f);
            float xx1 = fmaxf(bi.x, bj.x);
            float yy1 = fmaxf(bi.y, bj.y);
            float xx2 = fminf(bi.z, bj.z);
            float yy2 = fminf(bi.w, bj.w);
            float inter = fmaxf(xx2 - xx1, 0.0f) * fmaxf(yy2 - yy1, 0.0f);
            float denom = ai + aj;
            denom = denom - inter;
            denom = denom + 1e-9f;
            float iou = inter / denom;
            if (iou > th) { suppressed = true; break; }
          }
          if (suppressed) atomicAnd(&sm.keepw[j >> 5], ~(1u << (j & 31)));
        }
      }
    }
    __syncthreads();
  }

  if (tid < NWORDS && tid >= TR * 2) sm.keepw[tid] = 0;
  __syncthreads();
  if (tid == 0) {
    int r = 0;
    for (int w = 0; w < NWORDS && r < MAXDET; ++w) {
      unsigned bits = sm.keepw[w];
      while (bits && r < MAXDET) {
        int l = __builtin_ctz(bits);
        bits &= bits - 1;
        sm.kept_pos[r++] = w * 32 + l;
      }
    }
    sm.scal[3] = r;
  }
  __syncthreads();
  const int K = sm.scal[3];

  float4* obx = (float4*)out;
  float*  osc = out + (size_t)B * MAXDET * 4;
  float*  olb = osc + (size_t)B * MAXDET;
  float*  ovl = olb + (size_t)B * MAXDET;
  for (int r = tid; r < MAXDET; r += NTHR) {
    size_t slot = (size_t)b * MAXDET + r;
    if (r < K) {
      int i    = sm.kept_pos[r];
      int orig = so[i];
      float4 bb = ((const float4*)bx)[orig];
      bb.x = clipf(bb.x, fimg);
      bb.y = clipf(bb.y, fimg);
      bb.z = clipf(bb.z, fimg);
      bb.w = clipf(bb.w, fimg);
      obx[slot] = bb;
      osc[slot] = sc[orig];
      olb[slot] = (float)lb[orig];
      ovl[slot] = 1.0f;
    } else {
      obx[slot] = make_float4(0.f, 0.f, 0.f, 0.f);
      osc[slot] = 0.0f;
      olb[slot] = 0.0f;
      ovl[slot] = 0.0f;
    }
  }
}

extern "C" void kernel_launch(void* const* d_in, const int* in_sizes, int n_in,
                              void* d_out, int out_size, void* d_ws, size_t ws_size,
                              hipStream_t stream) {
  const float* boxes      = (const float*)d_in[0];
  const float* scores     = (const float*)d_in[1];
  const int*   labels     = (const int*)d_in[2];
  const float* nms_thresh = (const float*)d_in[3];
  const float* cls_w      = (const float*)d_in[4];
  const int*   img_sz     = (const int*)d_in[5];

  int B = out_size / (MAXDET * 7);
  int N = in_sizes[1] / B;               // 4096

  // ws layout
  size_t off_sorted = 0;
  size_t off_V      = (off_sorted + (size_t)B * N * 4 + 255) & ~(size_t)255;
  size_t off_Vseg   = off_V + (size_t)B * 4;
  size_t off_done   = off_Vseg + (size_t)B * 16;
  size_t off_total  = off_done + (size_t)B * 4;
  size_t off_Kf     = off_total + (size_t)B * 4;
  size_t off_kept   = off_Kf + (size_t)B * 4;
  size_t off_kw     = (off_kept + (size_t)B * MAXDET * 4 + 255) & ~(size_t)255;
  size_t off_obox   = (off_kw + (size_t)B * 64 * 8 + 255) & ~(size_t)255;
  size_t off_area   = off_obox + (size_t)B * NBOX * 16;
  size_t off_keys   = (off_area + (size_t)B * NBOX * 4 + 255) & ~(size_t)255;
  size_t off_tr     = (off_keys + (size_t)B * NBOX * 8 + 255) & ~(size_t)255;
  size_t sz_tr      = (size_t)B * 64 * NBOX * 8;   // 32 MiB at B=16
  size_t need_fast  = off_tr + sz_tr;

  int*    ws_sorted = (int*)((char*)d_ws + off_sorted);
  int*    ws_V      = (int*)((char*)d_ws + off_V);
  int*    ws_Vseg   = (int*)((char*)d_ws + off_Vseg);
  int*    ws_done   = (int*)((char*)d_ws + off_done);
  int*    ws_total  = (int*)((char*)d_ws + off_total);
  int*    ws_K      = (int*)((char*)d_ws + off_Kf);
  int*    ws_kept   = (int*)((char*)d_ws + off_kept);
  ull*    ws_keptw  = (ull*)((char*)d_ws + off_kw);
  float4* obox      = (float4*)((char*)d_ws + off_obox);
  float*  area      = (float*)((char*)d_ws + off_area);
  ull*    ws_keys   = (ull*)((char*)d_ws + off_keys);
  ull*    trans     = (ull*)((char*)d_ws + off_tr);

  if (ws_size >= need_fast && N == NBOX) {
    sort_seg<<<dim3(4, B), dim3(256), 0, stream>>>(scores, labels, cls_w,
                                                   ws_keys, ws_Vseg, N);
    merge_top<<<dim3(B), dim3(512), 0, stream>>>(ws_keys, ws_Vseg, boxes, labels,
                                                 img_sz, ws_sorted, ws_V, ws_done,
                                                 obox, area, N);
    // chunk 0: tiles [0,16)
    suptr_chunk<<<dim3(136, B), dim3(256), 0, stream>>>(
        obox, area, nms_thresh, ws_V, ws_done, trans, 0);
    resolve_jac<<<dim3(B), dim3(NTHR), 0, stream>>>(
        ws_V, trans, ws_done, ws_total, ws_keptw, ws_kept, ws_K, 0, 16);
    // rare path: finish the sort (ranks 1024+), then chunks 1..3
    merge_full<<<dim3(B), dim3(NTHR), 0, stream>>>(
        ws_keys, ws_done, boxes, labels, img_sz, ws_sorted, obox, area, N);
    suptr_chunk<<<dim3(392, B), dim3(256), 0, stream>>>(
        obox, area, nms_thresh, ws_V, ws_done, trans, 16);
    resolve_jac<<<dim3(B), dim3(NTHR), 0, stream>>>(
        ws_V, trans, ws_done, ws_total, ws_keptw, ws_kept, ws_K, 16, 32);
    suptr_chunk<<<dim3(648, B), dim3(256), 0, stream>>>(
        obox, area, nms_thresh, ws_V, ws_done, trans, 32);
    resolve_jac<<<dim3(B), dim3(NTHR), 0, stream>>>(
        ws_V, trans, ws_done, ws_total, ws_keptw, ws_kept, ws_K, 32, 48);
    suptr_chunk<<<dim3(904, B), dim3(256), 0, stream>>>(
        obox, area, nms_thresh, ws_V, ws_done, trans, 48);
    resolve_jac<<<dim3(B), dim3(NTHR), 0, stream>>>(
        ws_V, trans, ws_done, ws_total, ws_keptw, ws_kept, ws_K, 48, 64);

    write_out<<<dim3(B), dim3(256), 0, stream>>>(
        boxes, scores, labels, img_sz, (float*)d_out, B, N,
        ws_sorted, ws_K, ws_kept);
  } else {
    // fallback: full sort via S1+M+R1, then monolithic NMS
    sort_seg<<<dim3(4, B), dim3(256), 0, stream>>>(scores, labels, cls_w,
                                                   ws_keys, ws_Vseg, N);
    merge_top<<<dim3(B), dim3(512), 0, stream>>>(ws_keys, ws_Vseg, boxes, labels,
                                                 img_sz, ws_sorted, ws_V, ws_done,
                                                 obox, area, N);
    merge_full<<<dim3(B), dim3(NTHR), 0, stream>>>(
        ws_keys, ws_done, boxes, labels, img_sz, ws_sorted, obox, area, N);
    float4* ws_ovf = (float4*)((char*)d_ws + off_keys);  // reuse keys tail region
    nms_kernel<<<dim3(B), dim3(NTHR), 0, stream>>>(boxes, scores, labels,
                                                   nms_thresh, cls_w, img_sz,
                                                   (float*)d_out, B, N,
                                                   ws_sorted, ws_V, ws_ovf);
  }
}

// Round 14
// 58.556 us; speedup vs baseline: 3.7806x; 1.2938x over previous
//
#include <hip/hip_runtime.h>
#include <math.h>

#define NBOX   4096
#define NTHR   1024
#define MAXDET 300
#define CAP    3968          // fallback path
#define NWORDS (NBOX / 32)

typedef unsigned long long ull;

__device__ __forceinline__ float clipf(float v, float hi) {
  return fminf(fmaxf(v, 0.0f), hi);
}

__device__ __forceinline__ float getimg(const int* img_i) {
  int iv = *img_i;
  return (iv > 0 && iv < (1 << 24)) ? (float)iv : __int_as_float(iv);
}

// comparator macros: "up" (e&K)==0 => descending run (matches argsort(-key))
#define CSWAP_REG(va, vb, eo, K) { int e_ = wbase + (eo) + lane;                     \
    if ((((e_) & (K)) == 0) ? ((va) < (vb)) : ((va) > (vb))) { ull t_=(va); (va)=(vb); (vb)=t_; } }
#define CSWAP_SHFL(vr, eo, K) { int e_ = wbase + (eo) + lane;                        \
    ull c_ = __shfl_xor((vr), j);                                                    \
    bool km_ = ((((e_) & (K)) == 0) == ((lane & j) == 0));                           \
    (vr) = km_ ? ((vr) > c_ ? (vr) : c_) : ((vr) < c_ ? (vr) : c_); }
#define LOCALPHASES(jmax, K) { for (int j = (jmax); j >= 1; j >>= 1) {               \
    if (j == 128)      { CSWAP_REG(v0, v2, 0, K);  CSWAP_REG(v1, v3, 64, K);  }      \
    else if (j == 64)  { CSWAP_REG(v0, v1, 0, K);  CSWAP_REG(v2, v3, 128, K); }      \
    else { CSWAP_SHFL(v0, 0, K); CSWAP_SHFL(v1, 64, K); CSWAP_SHFL(v2, 128, K); CSWAP_SHFL(v3, 192, K); } } }

__device__ __forceinline__ void emit_one(ull key, int l, int b, int N,
    const float* boxes, const int* labels, float fimg, float offs,
    int* ws_sorted, float4* obox, float* area)
{
  unsigned orig = 0xFFFFFFFFu - (unsigned)(key & 0xFFFFFFFFull);
  ws_sorted[(size_t)b * N + l] = (int)orig;
  const float4* bx4 = (const float4*)(boxes + (size_t)b * N * 4);
  float4 bb = bx4[orig];
  float off = (float)labels[(size_t)b * N + orig] * offs;
  bb.x = clipf(bb.x, fimg) + off;
  bb.y = clipf(bb.y, fimg) + off;
  bb.z = clipf(bb.z, fimg) + off;
  bb.w = clipf(bb.w, fimg) + off;
  obox[(size_t)b * NBOX + l] = bb;
  area[(size_t)b * NBOX + l] = fmaxf(bb.z - bb.x, 0.0f) * fmaxf(bb.w - bb.y, 0.0f);
}

// =================== S1: per-1024-segment key build + bitonic sort (descending) ===================
__global__ __launch_bounds__(256)
void sort_seg(const float* __restrict__ scores,
              const int*   __restrict__ labels,
              const float* __restrict__ cls_w,
              ull* __restrict__ ws_keys,
              int* __restrict__ ws_Vseg,
              int N)
{
  __shared__ ull ks[1024];
  __shared__ int cnt;
  const int b = blockIdx.y, s = blockIdx.x;
  const int tid = threadIdx.x, lane = tid & 63, wave = tid >> 6;
  const int wbase = wave * 256;
  const int base  = s * 1024;
  const float* sc = scores + (size_t)b * N;
  const int*   lb = labels + (size_t)b * N;
  if (tid == 0) cnt = 0;

  ull v0, v1, v2, v3;
  int vc = 0;
  #define BUILD(vm, mo) { int l_ = wbase + (mo) + lane; int gi = base + l_;          \
      float sv = sc[gi]; ull key = (ull)(0xFFFFFFFFu - (unsigned)gi);                \
      if (sv > 0.3f) { float w_ = sv * cls_w[lb[gi]]; unsigned ub = __float_as_uint(w_); \
        ub = (ub & 0x80000000u) ? ~ub : (ub | 0x80000000u);                          \
        key |= ((ull)ub << 32); ++vc; }                                              \
      vm = key; }
  BUILD(v0, 0) BUILD(v1, 64) BUILD(v2, 128) BUILD(v3, 192)
  #undef BUILD
  atomicAdd(&cnt, vc);

  for (int k2 = 2; k2 <= 256; k2 <<= 1) { LOCALPHASES(k2 >> 1, k2); }

  #define STV { ks[wbase + lane] = v0; ks[wbase + 64 + lane] = v1;                   \
                ks[wbase + 128 + lane] = v2; ks[wbase + 192 + lane] = v3; }
  #define LDV { v0 = ks[wbase + lane]; v1 = ks[wbase + 64 + lane];                   \
                v2 = ks[wbase + 128 + lane]; v3 = ks[wbase + 192 + lane]; }
  #define CROSS(J, K) { for (int i = tid; i < 1024; i += 256) { int l2 = i ^ (J);    \
      if (l2 > i) { ull a = ks[i], c = ks[l2];                                       \
        if ((((i) & (K)) == 0) ? (a < c) : (a > c)) { ks[i] = c; ks[l2] = a; } } } }

  STV; __syncthreads();
  CROSS(256, 512); __syncthreads();
  LDV; LOCALPHASES(128, 512);
  STV; __syncthreads();
  CROSS(512, 1024); __syncthreads();
  CROSS(256, 1024); __syncthreads();
  LDV; LOCALPHASES(128, 1024);

  ull* kb = ws_keys + (size_t)b * NBOX + base;
  kb[wbase + lane]       = v0;
  kb[wbase + 64 + lane]  = v1;
  kb[wbase + 128 + lane] = v2;
  kb[wbase + 192 + lane] = v3;
  __syncthreads();
  if (tid == 0) ws_Vseg[b * 4 + s] = cnt;
  #undef STV
  #undef LDV
  #undef CROSS
}

// =================== M: tournament top-1024 merge + fused prep (ranks 0..1023) ===================
__global__ __launch_bounds__(512)
void merge_top(const ull* __restrict__ ws_keys,
               const int* __restrict__ ws_Vseg,
               const float* __restrict__ boxes,
               const int*   __restrict__ labels,
               const int*   __restrict__ img_i,
               int*    __restrict__ ws_sorted,
               int*    __restrict__ ws_V,
               int*    __restrict__ ws_done,
               float4* __restrict__ obox,
               float*  __restrict__ area,
               int N)
{
  __shared__ ull ksh[2][1024];
  const int b = blockIdx.x;
  const int tid = threadIdx.x, lane = tid & 63, wave = tid >> 6;
  const int g = wave >> 2, wv = wave & 3;
  const int wbase = wv * 256;
  const ull* kb = ws_keys + (size_t)b * NBOX;

  ull v0, v1, v2, v3;
  #define PMAX(vm, mo) { int l_ = wbase + (mo) + lane;                               \
      ull a = kb[g * 2048 + l_]; ull c = kb[g * 2048 + 1024 + (1023 - l_)];          \
      vm = (a > c) ? a : c; }
  PMAX(v0, 0) PMAX(v1, 64) PMAX(v2, 128) PMAX(v3, 192)
  #undef PMAX

  #define STVG(arr) { (arr)[wbase + lane] = v0; (arr)[wbase + 64 + lane] = v1;       \
                      (arr)[wbase + 128 + lane] = v2; (arr)[wbase + 192 + lane] = v3; }
  #define LDVG(arr) { v0 = (arr)[wbase + lane]; v1 = (arr)[wbase + 64 + lane];       \
                      v2 = (arr)[wbase + 128 + lane]; v3 = (arr)[wbase + 192 + lane]; }
  #define MCROSS(arr, J) { for (int i = (tid & 255); i < 1024; i += 256) {           \
      int l2 = i ^ (J); if (l2 > i) { ull a = (arr)[i], c = (arr)[l2];               \
        if (a < c) { (arr)[i] = c; (arr)[l2] = a; } } } }

  STVG(ksh[g]); __syncthreads();
  MCROSS(ksh[g], 512); __syncthreads();
  MCROSS(ksh[g], 256); __syncthreads();
  LDVG(ksh[g]); LOCALPHASES(128, 2048);
  STVG(ksh[g]); __syncthreads();

  if (g == 0) {
    #define PMAX2(vm, mo) { int l_ = wbase + (mo) + lane;                            \
        ull a = ksh[0][l_]; ull c = ksh[1][1023 - l_]; vm = (a > c) ? a : c; }
    PMAX2(v0, 0) PMAX2(v1, 64) PMAX2(v2, 128) PMAX2(v3, 192)
    #undef PMAX2
  }
  __syncthreads();
  if (g == 0) STVG(ksh[0]);
  __syncthreads();
  if (tid < 256) MCROSS(ksh[0], 512);
  __syncthreads();
  if (tid < 256) MCROSS(ksh[0], 256);
  __syncthreads();

  if (g == 0) {
    LDVG(ksh[0]); LOCALPHASES(128, 2048);
    float fimg = getimg(img_i);
    float offs = fimg + 1.0f;
    emit_one(v0, wbase + lane,       b, N, boxes, labels, fimg, offs, ws_sorted, obox, area);
    emit_one(v1, wbase + 64 + lane,  b, N, boxes, labels, fimg, offs, ws_sorted, obox, area);
    emit_one(v2, wbase + 128 + lane, b, N, boxes, labels, fimg, offs, ws_sorted, obox, area);
    emit_one(v3, wbase + 192 + lane, b, N, boxes, labels, fimg, offs, ws_sorted, obox, area);
  }
  if (tid == 0) {
    ws_V[b] = ws_Vseg[b * 4] + ws_Vseg[b * 4 + 1] + ws_Vseg[b * 4 + 2] + ws_Vseg[b * 4 + 3];
    ws_done[b] = 0;
  }
  #undef STVG
  #undef LDVG
  #undef MCROSS
}

// =================== T: transposed suppression words for chunk 0 (w<16, j<1024) ===================
// trans[b][w][j] : bit r = cond(i = w*64+r, j)
__global__ __launch_bounds__(256)
void suptr0(const float4* __restrict__ obox,
            const float*  __restrict__ area,
            const float*  __restrict__ nms_th,
            const int*    __restrict__ ws_V,
            ull* __restrict__ trans)
{
  __shared__ float4 rbox[64];
  __shared__ float  rarea[64];
  __shared__ ull    part[4][64];
  const int b = blockIdx.y;
  int rem = blockIdx.x, d = 0;
  while (rem >= d + 1) { rem -= d + 1; ++d; }
  const int jt = d, w = rem;        // jt in [0,16), w <= jt
  const int V = ws_V[b];
  if (jt * 64 >= V) return;
  const int JW = (V + 63) >> 6;
  if (w >= JW) return;

  const int tid = threadIdx.x, wave = tid >> 6, lane = tid & 63;
  double xt = (double)(*nms_th);
  float  th = (float)(1.0 / (1.0 + exp(-xt)));
  const float4* ob = obox + (size_t)b * NBOX;
  const float*  ar = area + (size_t)b * NBOX;

  if (tid < 64) { rbox[tid] = ob[w * 64 + tid]; rarea[tid] = ar[w * 64 + tid]; }
  __syncthreads();

  const int j = jt * 64 + lane;
  const float4 bj = ob[j];
  const float  aj = ar[j];
  ull p = 0;
  #pragma unroll 4
  for (int rr = 0; rr < 16; ++rr) {
    const int r = wave * 16 + rr;
    const int i = w * 64 + r;
    const float4 bi = rbox[r];
    const float  ai = rarea[r];
    float xx1 = fmaxf(bi.x, bj.x);
    float yy1 = fmaxf(bi.y, bj.y);
    float xx2 = fminf(bi.z, bj.z);
    float yy2 = fminf(bi.w, bj.w);
    float inter = fmaxf(xx2 - xx1, 0.0f) * fmaxf(yy2 - yy1, 0.0f);
    float denom = ai + aj;           // ((areas[i]+areas[j]) - inter) + 1e-9, ref order
    denom = denom - inter;
    denom = denom + 1e-9f;
    float iou = inter / denom;
    bool cond = (iou > th) && (j > i);
    p |= cond ? (1ull << r) : 0ull;
  }
  part[wave][lane] = p;
  __syncthreads();
  if (tid < 64)
    trans[(size_t)b * 16 * NBOX + (size_t)w * NBOX + jt * 64 + tid] =
        (part[0][tid] | part[1][tid]) | (part[2][tid] | part[3][tid]);
}

// =================== R0: Jacobi resolve for chunk 0 (+ fused output on finalize) ===================
__global__ __launch_bounds__(NTHR)
void resolve0(const float* __restrict__ boxes,
              const float* __restrict__ scores,
              const int*   __restrict__ labels,
              const int*   __restrict__ img_i,
              const int*   __restrict__ ws_V,
              const ull*   __restrict__ trans,
              int* __restrict__ ws_done,
              int* __restrict__ ws_total,
              ull* __restrict__ ws_keptw,
              int* __restrict__ ws_K,
              const int* __restrict__ ws_sorted,
              float* __restrict__ out,
              int B, int N)
{
  __shared__ ull aw[16];
  __shared__ ull kw[16];
  __shared__ int kept_sh[MAXDET];
  __shared__ int flag, fin, Ktot;

  const int b = blockIdx.x;
  const int tid = threadIdx.x, wave = tid >> 6, lane = tid & 63;
  const int V = ws_V[b], JW = (V + 63) >> 6;
  const int j = tid;
  const ull* tb = trans + (size_t)b * 16 * NBOX;

  ull supT[16];
  #pragma unroll
  for (int w = 0; w < 16; ++w)
    supT[w] = (w <= wave) ? tb[(size_t)w * NBOX + j] : 0ull;

  const bool a0 = (j < V);
  { ull bw0 = __ballot(a0); if (lane == 0) aw[wave] = bw0; }
  __syncthreads();

  for (;;) {
    ull s = 0;
    #pragma unroll
    for (int w = 0; w < 16; ++w) s |= aw[w] & supT[w];
    const bool keep = a0 && (s == 0ull);
    const ull bw = __ballot(keep);
    const bool diff = (lane == 0) && (bw != aw[wave]);
    __syncthreads();
    if (tid == 0) flag = 0;
    __syncthreads();
    if (diff) { aw[wave] = bw; flag = 1; }
    __syncthreads();
    if (!flag) break;
  }

  if (wave == 0) {
    ull w64 = (lane < 16) ? aw[lane] : 0ull;
    int pc = __popcll(w64), incl = pc;
    #pragma unroll
    for (int s2 = 1; s2 < 64; s2 <<= 1) { int v = __shfl_up(incl, s2); if (lane >= s2) incl += v; }
    const int totalALL = __shfl(incl, 63);
    const bool fi = (totalALL >= MAXDET) || (16 >= JW);
    if (fi) {
      int cumprev = incl - pc;
      int room = MAXDET - cumprev; if (room < 0) room = 0;
      int nk = (room < pc) ? room : pc;
      if (nk == 0) w64 = 0;
      else while (pc > nk) { int msb = 63 - __builtin_clzll(w64); w64 &= ~(1ull << msb); --pc; }
    }
    if (lane < 16) { kw[lane] = w64; ws_keptw[(size_t)b * 64 + lane] = w64; }
    if (lane == 0) { fin = fi ? 1 : 0; Ktot = (totalALL < MAXDET) ? totalALL : MAXDET; }
  }
  __syncthreads();

  if (!fin) { if (tid == 0) ws_total[b] = Ktot; return; }

  if (wave == 0) {
    ull km = (lane < 16) ? kw[lane] : 0ull;
    int pc = __popcll(km), incl = pc;
    #pragma unroll
    for (int s2 = 1; s2 < 64; s2 <<= 1) { int v = __shfl_up(incl, s2); if (lane >= s2) incl += v; }
    int base = incl - pc;
    while (km) { int l = __builtin_ctzll(km); km &= km - 1; kept_sh[base++] = lane * 64 + l; }
  }
  __syncthreads();

  const int K = Ktot;
  float fimg = getimg(img_i);
  const float* bx = boxes  + (size_t)b * N * 4;
  const float* sc = scores + (size_t)b * N;
  const int*   lb = labels + (size_t)b * N;
  const int*   so = ws_sorted + (size_t)b * N;
  float4* obx = (float4*)out;
  float*  osc = out + (size_t)B * MAXDET * 4;
  float*  olb = osc + (size_t)B * MAXDET;
  float*  ovl = olb + (size_t)B * MAXDET;
  for (int rI = tid; rI < MAXDET; rI += NTHR) {
    size_t slot = (size_t)b * MAXDET + rI;
    if (rI < K) {
      int i    = kept_sh[rI];
      int orig = so[i];
      float4 bb = ((const float4*)bx)[orig];
      bb.x = clipf(bb.x, fimg);
      bb.y = clipf(bb.y, fimg);
      bb.z = clipf(bb.z, fimg);
      bb.w = clipf(bb.w, fimg);
      obx[slot] = bb;
      osc[slot] = sc[orig];
      olb[slot] = (float)lb[orig];
      ovl[slot] = 1.0f;
    } else {
      obx[slot] = make_float4(0.f, 0.f, 0.f, 0.f);
      osc[slot] = 0.0f;
      olb[slot] = 0.0f;
      ovl[slot] = 0.0f;
    }
  }
  if (tid == 0) { ws_K[b] = K; ws_done[b] = 1; }
}

// =================== C: rare-path cleanup — full merge + chunks 1..3 + outputs, one kernel ===================
__global__ __launch_bounds__(NTHR)
void cleanup_kernel(const ull* __restrict__ ws_keys,
                    const float* __restrict__ boxes,
                    const float* __restrict__ scores,
                    const int*   __restrict__ labels,
                    const int*   __restrict__ img_i,
                    const float* __restrict__ nms_th,
                    const int* __restrict__ ws_V,
                    int* __restrict__ ws_done,
                    const int* __restrict__ ws_total,
                    const ull* __restrict__ ws_keptw,
                    const float4* __restrict__ obox,
                    int* __restrict__ ws_K,
                    float* __restrict__ out,
                    int B, int N)
{
  __shared__ ull    K[4096];        // 32 KB merged keys
  __shared__ float4 rb[1024];       // current-chunk rows (offset boxes)
  __shared__ float  ra[1024];
  __shared__ float4 kbox[MAXDET];   // kept-box cache
  __shared__ float  karea[MAXDET];
  __shared__ ull    aw[16];
  __shared__ ull    kw[64];
  __shared__ int    kept_sh[MAXDET];
  __shared__ int    flag, fin, Ktot;

  const int b = blockIdx.x;
  if (ws_done[b]) return;           // common case: ~free
  const int tid = threadIdx.x, wave = tid >> 6, lane = tid & 63;
  const int V = ws_V[b], JW = (V + 63) >> 6;
  float fimg = getimg(img_i);
  float offs = fimg + 1.0f;
  double xt = (double)(*nms_th);
  float th = (float)(1.0 / (1.0 + exp(-xt)));

  // ---- full 4-way bitonic merge of segment-sorted keys (proven network) ----
  const ull* kb = ws_keys + (size_t)b * NBOX;
  for (int i = tid; i < 4096; i += NTHR) K[i] = kb[i];
  __syncthreads();
  { int i = tid;
    { ull a = K[i], c = K[2047 - i];        if (a < c) { K[i] = c; K[2047 - i] = a; } }
    { ull a = K[2048 + i], c = K[4095 - i]; if (a < c) { K[2048 + i] = c; K[4095 - i] = a; } } }
  __syncthreads();
  for (int j2 = 512; j2 >= 1; j2 >>= 1) {
    for (int idx = tid; idx < 4096; idx += NTHR) {
      int l = idx ^ j2;
      if (l > idx) { ull a = K[idx], c = K[l]; if (a < c) { K[idx] = c; K[l] = a; } } }
    __syncthreads(); }
  for (int m = 0; m < 2; ++m) {
    int i2 = tid + m * NTHR;
    ull a = K[i2], c = K[4095 - i2];
    if (a < c) { K[i2] = c; K[4095 - i2] = a; } }
  __syncthreads();
  for (int j2 = 1024; j2 >= 1; j2 >>= 1) {
    for (int idx = tid; idx < 4096; idx += NTHR) {
      int l = idx ^ j2;
      if (l > idx) { ull a = K[idx], c = K[l]; if (a < c) { K[idx] = c; K[l] = a; } } }
    __syncthreads(); }

  // ---- carry chunk-0 state; build kept list + kept-box cache ----
  int total = ws_total[b];
  const ull* kwg = ws_keptw + (size_t)b * 64;
  if (tid < 64) kw[tid] = (tid < 16) ? kwg[tid] : 0ull;
  __syncthreads();
  if (wave == 0) {
    ull km = (lane < 16) ? kw[lane] : 0ull;
    int pc = __popcll(km), incl = pc;
    #pragma unroll
    for (int s2 = 1; s2 < 64; s2 <<= 1) { int v = __shfl_up(incl, s2); if (lane >= s2) incl += v; }
    int base = incl - pc;
    while (km) { int l = __builtin_ctzll(km); km &= km - 1; kept_sh[base++] = lane * 64 + l; }
  }
  __syncthreads();
  for (int k = tid; k < total; k += NTHR) {
    float4 bb = obox[(size_t)b * NBOX + kept_sh[k]];   // ranks <1024, written by merge_top
    kbox[k]  = bb;
    karea[k] = fmaxf(bb.z - bb.x, 0.0f) * fmaxf(bb.w - bb.y, 0.0f);
  }
  __syncthreads();

  // ---- chunks 1..3 ----
  for (int c = 1; c < 4; ++c) {
    const int t0 = 16 * c, t1 = t0 + 16;
    // stage this chunk's 1024 rows from merged keys (no global RAW)
    {
      int gi = t0 * 64 + tid;
      unsigned orig = 0xFFFFFFFFu - (unsigned)(K[gi] & 0xFFFFFFFFull);
      float4 bb = ((const float4*)(boxes + (size_t)b * N * 4))[orig];
      float off = (float)labels[(size_t)b * N + orig] * offs;
      bb.x = clipf(bb.x, fimg) + off;
      bb.y = clipf(bb.y, fimg) + off;
      bb.z = clipf(bb.z, fimg) + off;
      bb.w = clipf(bb.w, fimg) + off;
      rb[tid] = bb;
      ra[tid] = fmaxf(bb.z - bb.x, 0.0f) * fmaxf(bb.w - bb.y, 0.0f);
    }
    __syncthreads();

    const int j = t0 * 64 + tid;
    const float4 bj = rb[tid];
    const float  aj = ra[tid];

    // in-chunk suppressed-by words on the fly (rows from rb/ra)
    ull supT[16];
    for (int w = 0; w < 16; ++w) {
      ull word = 0;
      if (w <= wave) {
        for (int rr = 0; rr < 64; ++rr) {
          const int lr = w * 64 + rr;
          const float4 bi = rb[lr];
          const float  ai = ra[lr];
          float xx1 = fmaxf(bi.x, bj.x);
          float yy1 = fmaxf(bi.y, bj.y);
          float xx2 = fminf(bi.z, bj.z);
          float yy2 = fminf(bi.w, bj.w);
          float inter = fmaxf(xx2 - xx1, 0.0f) * fmaxf(yy2 - yy1, 0.0f);
          float denom = ai + aj;
          denom = denom - inter;
          denom = denom + 1e-9f;
          float iou = inter / denom;
          bool cond = (iou > th) && (tid > lr);     // j > i
          word |= cond ? (1ull << rr) : 0ull;
        }
      }
      supT[w] = word;
    }
    // catch-up vs all finalized kept (ranks < t0*64, so i < j always)
    bool cat = false;
    for (int k = 0; k < total && !cat; ++k) {
      const float4 bi = kbox[k];
      const float  ai = karea[k];
      float xx1 = fmaxf(bi.x, bj.x);
      float yy1 = fmaxf(bi.y, bj.y);
      float xx2 = fminf(bi.z, bj.z);
      float yy2 = fminf(bi.w, bj.w);
      float inter = fmaxf(xx2 - xx1, 0.0f) * fmaxf(yy2 - yy1, 0.0f);
      float denom = ai + aj;
      denom = denom - inter;
      denom = denom + 1e-9f;
      float iou = inter / denom;
      if (iou > th) cat = true;
    }
    const bool a0 = (j < V) && !cat;
    { ull bw0 = __ballot(a0); if (lane == 0) aw[wave] = bw0; }
    __syncthreads();

    // Jacobi to fixpoint (identical logic to resolve0)
    for (;;) {
      ull s = 0;
      #pragma unroll
      for (int w = 0; w < 16; ++w) s |= aw[w] & supT[w];
      const bool keep = a0 && (s == 0ull);
      const ull bw = __ballot(keep);
      const bool diff = (lane == 0) && (bw != aw[wave]);
      __syncthreads();
      if (tid == 0) flag = 0;
      __syncthreads();
      if (diff) { aw[wave] = bw; flag = 1; }
      __syncthreads();
      if (!flag) break;
    }

    // trim + persist to kw
    if (wave == 0) {
      ull w64 = (lane < 16) ? aw[lane] : 0ull;
      int pc = __popcll(w64), incl = pc;
      #pragma unroll
      for (int s2 = 1; s2 < 64; s2 <<= 1) { int v = __shfl_up(incl, s2); if (lane >= s2) incl += v; }
      const int totalALL = total + __shfl(incl, 63);
      const bool fi = (totalALL >= MAXDET) || (t1 >= JW);
      if (fi) {
        int cumprev = total + incl - pc;
        int room = MAXDET - cumprev; if (room < 0) room = 0;
        int nk = (room < pc) ? room : pc;
        if (nk == 0) { w64 = 0; pc = 0; }
        else while (pc > nk) { int msb = 63 - __builtin_clzll(w64); w64 &= ~(1ull << msb); --pc; }
      }
      if (lane < 16) kw[t0 + lane] = w64;
      if (lane == 0) { fin = fi ? 1 : 0; Ktot = (totalALL < MAXDET) ? totalALL : MAXDET; }
    }
    __syncthreads();

    // append new kept (positions + boxes from rb/ra)
    if (wave == 0) {
      ull km = (lane < 16) ? kw[t0 + lane] : 0ull;
      int pc = __popcll(km), incl = pc;
      #pragma unroll
      for (int s2 = 1; s2 < 64; s2 <<= 1) { int v = __shfl_up(incl, s2); if (lane >= s2) incl += v; }
      int base = total + incl - pc;
      while (km) { int l = __builtin_ctzll(km); km &= km - 1; kept_sh[base++] = (t0 + lane) * 64 + l; }
    }
    __syncthreads();
    const int newtotal = Ktot;
    for (int k = total + tid; k < newtotal; k += NTHR) {
      int lr = kept_sh[k] - t0 * 64;
      kbox[k]  = rb[lr];
      karea[k] = ra[lr];
    }
    total = newtotal;
    __syncthreads();
    if (fin) break;
  }

  // ---- outputs (orig indices straight from merged keys) ----
  const int Kf = total;
  const float* bx = boxes  + (size_t)b * N * 4;
  const float* sc = scores + (size_t)b * N;
  const int*   lb = labels + (size_t)b * N;
  float4* obx = (float4*)out;
  float*  osc = out + (size_t)B * MAXDET * 4;
  float*  olb = osc + (size_t)B * MAXDET;
  float*  ovl = olb + (size_t)B * MAXDET;
  for (int rI = tid; rI < MAXDET; rI += NTHR) {
    size_t slot = (size_t)b * MAXDET + rI;
    if (rI < Kf) {
      int i = kept_sh[rI];
      unsigned orig = 0xFFFFFFFFu - (unsigned)(K[i] & 0xFFFFFFFFull);
      float4 bb = ((const float4*)bx)[orig];
      bb.x = clipf(bb.x, fimg);
      bb.y = clipf(bb.y, fimg);
      bb.z = clipf(bb.z, fimg);
      bb.w = clipf(bb.w, fimg);
      obx[slot] = bb;
      osc[slot] = sc[orig];
      olb[slot] = (float)lb[orig];
      ovl[slot] = 1.0f;
    } else {
      obx[slot] = make_float4(0.f, 0.f, 0.f, 0.f);
      osc[slot] = 0.0f;
      olb[slot] = 0.0f;
      ovl[slot] = 0.0f;
    }
  }
  if (tid == 0) { ws_K[b] = Kf; ws_done[b] = 1; }
}

// =================== R1: full 4-way merge (fallback path only) ===================
__global__ __launch_bounds__(NTHR)
void merge_full(const ull* __restrict__ ws_keys,
                const float* __restrict__ boxes,
                const int*   __restrict__ labels,
                const int*   __restrict__ img_i,
                int*    __restrict__ ws_sorted,
                float4* __restrict__ obox,
                float*  __restrict__ area,
                int N)
{
  __shared__ ull K[4096];
  const int b = blockIdx.x;
  const int tid = threadIdx.x;
  const ull* kb = ws_keys + (size_t)b * NBOX;
  for (int i = tid; i < 4096; i += NTHR) K[i] = kb[i];
  __syncthreads();
  { int i = tid;
    { ull a = K[i], c = K[2047 - i];        if (a < c) { K[i] = c; K[2047 - i] = a; } }
    { ull a = K[2048 + i], c = K[4095 - i]; if (a < c) { K[2048 + i] = c; K[4095 - i] = a; } } }
  __syncthreads();
  for (int j = 512; j >= 1; j >>= 1) {
    for (int idx = tid; idx < 4096; idx += NTHR) {
      int l = idx ^ j;
      if (l > idx) { ull a = K[idx], c = K[l]; if (a < c) { K[idx] = c; K[l] = a; } } }
    __syncthreads(); }
  for (int m = 0; m < 2; ++m) {
    int i2 = tid + m * 1024;
    ull a = K[i2], c = K[4095 - i2];
    if (a < c) { K[i2] = c; K[4095 - i2] = a; } }
  __syncthreads();
  for (int j = 1024; j >= 1; j >>= 1) {
    for (int idx = tid; idx < 4096; idx += NTHR) {
      int l = idx ^ j;
      if (l > idx) { ull a = K[idx], c = K[l]; if (a < c) { K[idx] = c; K[l] = a; } } }
    __syncthreads(); }

  float fimg = getimg(img_i);
  float offs = fimg + 1.0f;
  for (int idx = 1024 + tid; idx < 4096; idx += NTHR)
    emit_one(K[idx], idx, b, N, boxes, labels, fimg, offs, ws_sorted, obox, area);
}

// =================== fallback kernel (round-2 path, used if ws too small) ===================
struct SMB {
  float4       obox[CAP];
  unsigned int keepw[NWORDS];
  int          kept_pos[MAXDET];
  int          scal[4];
};

__global__ __launch_bounds__(NTHR)
void nms_kernel(const float* __restrict__ boxes,
                const float* __restrict__ scores,
                const int*   __restrict__ labels,
                const float* __restrict__ nms_th,
                const float* __restrict__ cls_w,
                const int*   __restrict__ img_i,
                float* __restrict__ out,
                int B, int N,
                const int* __restrict__ ws_sorted,
                const int* __restrict__ ws_V,
                float4* __restrict__ ws_ovf)
{
  __shared__ SMB sm;
  const int b    = blockIdx.x;
  const int tid  = threadIdx.x;

  const float* bx = boxes  + (size_t)b * N * 4;
  const float* sc = scores + (size_t)b * N;
  const int*   lb = labels + (size_t)b * N;
  const int*   so = ws_sorted + (size_t)b * N;

  float fimg = getimg(img_i);
  float off_scale = fimg + 1.0f;
  double xt = (double)(*nms_th);
  float  th = (float)(1.0 / (1.0 + exp(-xt)));

  const int V = ws_V[b];
  if (tid < 4) sm.scal[tid] = 0;

  for (int m = 0; m < 4; ++m) {
    int i = tid + m * NTHR;
    int orig = so[i];
    float4 bb = ((const float4*)bx)[orig];
    float off = (float)lb[orig] * off_scale;
    bb.x = clipf(bb.x, fimg) + off;
    bb.y = clipf(bb.y, fimg) + off;
    bb.z = clipf(bb.z, fimg) + off;
    bb.w = clipf(bb.w, fimg) + off;
    if (i < CAP) sm.obox[i] = bb;
    else         ws_ovf[(size_t)b * (NBOX - CAP) + (i - CAP)] = bb;
  }
  for (int w = tid; w < NWORDS; w += NTHR) {
    int lo = w * 32;
    unsigned val;
    if      (V >= lo + 32) val = 0xFFFFFFFFu;
    else if (V <= lo)      val = 0u;
    else                   val = (1u << (V - lo)) - 1u;
    sm.keepw[w] = val;
  }
  __syncthreads();

  const int nt = (V + 63) >> 6;
  int TR = 0;
  for (int t = 0; t < nt; ++t) {
    if (tid < 64) {
      int i0 = t * 64;
      int me = i0 + tid;
      float4 bb = (me < CAP) ? sm.obox[me]
                             : ws_ovf[(size_t)b * (NBOX - CAP) + (me - CAP)];
      float arJ = fmaxf(bb.z - bb.x, 0.0f) * fmaxf(bb.w - bb.y, 0.0f);
      ull supby = 0;
      for (int l = 0; l < 64; ++l) {
        int i = i0 + l;
        float4 bi = (i < CAP) ? sm.obox[i]
                              : ws_ovf[(size_t)b * (NBOX - CAP) + (i - CAP)];
        float ai = fmaxf(bi.z - bi.x, 0.0f) * fmaxf(bi.w - bi.y, 0.0f);
        float xx1 = fmaxf(bi.x, bb.x);
        float yy1 = fmaxf(bi.y, bb.y);
        float xx2 = fminf(bi.z, bb.z);
        float yy2 = fminf(bi.w, bb.w);
        float inter = fmaxf(xx2 - xx1, 0.0f) * fmaxf(yy2 - yy1, 0.0f);
        float denom = ai + arJ;
        denom = denom - inter;
        denom = denom + 1e-9f;
        float iou = inter / denom;
        if (iou > th) supby |= (1ull << l);
      }
      ull alive = ((ull)sm.keepw[2 * t + 1] << 32) | sm.keepw[2 * t];
      ull rem = alive;
      while (rem) {
        int l = __builtin_ctzll(rem);
        rem &= rem - 1;
        ull sup = __ballot((supby >> l) & 1ull);
        sup &= ((~1ull) << l);
        sup &= alive;
        alive &= ~sup;
        rem   &= ~sup;
      }
      if (tid == 0) {
        sm.keepw[2 * t]     = (unsigned)alive;
        sm.keepw[2 * t + 1] = (unsigned)(alive >> 32);
        atomicAdd(&sm.scal[1], __builtin_popcountll(alive));
      }
    }
    __syncthreads();
    TR = t + 1;
    if (sm.scal[1] >= MAXDET) break;

    int jstart = (t + 1) * 64;
    if (jstart < V) {
      ull alive = ((ull)sm.keepw[2 * t + 1] << 32) | sm.keepw[2 * t];
      if (alive) {
        for (int j = jstart + tid; j < V; j += NTHR) {
          unsigned wj = sm.keepw[j >> 5];
          if (!((wj >> (j & 31)) & 1u)) continue;
          float4 bj = (j < CAP) ? sm.obox[j]
                                : ws_ovf[(size_t)b * (NBOX - CAP) + (j - CAP)];
          float aj = fmaxf(bj.z - bj.x, 0.0f) * fmaxf(bj.w - bj.y, 0.0f);
          ull rem = alive;
          bool suppressed = false;
          while (rem) {
            int l = __builtin_ctzll(rem);
            rem &= rem - 1;
            int i = t * 64 + l;
            float4 bi = (i < CAP) ? sm.obox[i]
                                  : ws_ovf[(size_t)b * (NBOX - CAP) + (i - CAP)];
            float ai = fmaxf(bi.z - bi.x, 0.0f) * fmaxf(bi.w - bi.y, 0.0f);
            float xx1 = fmaxf(bi.x, bj.x);
            float yy1 = fmaxf(bi.y, bj.y);
            float xx2 = fminf(bi.z, bj.z);
            float yy2 = fminf(bi.w, bj.w);
            float inter = fmaxf(xx2 - xx1, 0.0f) * fmaxf(yy2 - yy1, 0.0f);
            float denom = ai + aj;
            denom = denom - inter;
            denom = denom + 1e-9f;
            float iou = inter / denom;
            if (iou > th) { suppressed = true; break; }
          }
          if (suppressed) atomicAnd(&sm.keepw[j >> 5], ~(1u << (j & 31)));
        }
      }
    }
    __syncthreads();
  }

  if (tid < NWORDS && tid >= TR * 2) sm.keepw[tid] = 0;
  __syncthreads();
  if (tid == 0) {
    int r = 0;
    for (int w = 0; w < NWORDS && r < MAXDET; ++w) {
      unsigned bits = sm.keepw[w];
      while (bits && r < MAXDET) {
        int l = __builtin_ctz(bits);
        bits &= bits - 1;
        sm.kept_pos[r++] = w * 32 + l;
      }
    }
    sm.scal[3] = r;
  }
  __syncthreads();
  const int K = sm.scal[3];

  float4* obx = (float4*)out;
  float*  osc = out + (size_t)B * MAXDET * 4;
  float*  olb = osc + (size_t)B * MAXDET;
  float*  ovl = olb + (size_t)B * MAXDET;
  for (int r = tid; r < MAXDET; r += NTHR) {
    size_t slot = (size_t)b * MAXDET + r;
    if (r < K) {
      int i    = sm.kept_pos[r];
      int orig = so[i];
      float4 bb = ((const float4*)bx)[orig];
      bb.x = clipf(bb.x, fimg);
      bb.y = clipf(bb.y, fimg);
      bb.z = clipf(bb.z, fimg);
      bb.w = clipf(bb.w, fimg);
      obx[slot] = bb;
      osc[slot] = sc[orig];
      olb[slot] = (float)lb[orig];
      ovl[slot] = 1.0f;
    } else {
      obx[slot] = make_float4(0.f, 0.f, 0.f, 0.f);
      osc[slot] = 0.0f;
      olb[slot] = 0.0f;
      ovl[slot] = 0.0f;
    }
  }
}

extern "C" void kernel_launch(void* const* d_in, const int* in_sizes, int n_in,
                              void* d_out, int out_size, void* d_ws, size_t ws_size,
                              hipStream_t stream) {
  const float* boxes      = (const float*)d_in[0];
  const float* scores     = (const float*)d_in[1];
  const int*   labels     = (const int*)d_in[2];
  const float* nms_thresh = (const float*)d_in[3];
  const float* cls_w      = (const float*)d_in[4];
  const int*   img_sz     = (const int*)d_in[5];

  int B = out_size / (MAXDET * 7);
  int N = in_sizes[1] / B;               // 4096

  // ws layout
  size_t off_sorted = 0;
  size_t off_V      = (off_sorted + (size_t)B * N * 4 + 255) & ~(size_t)255;
  size_t off_Vseg   = off_V + (size_t)B * 4;
  size_t off_done   = off_Vseg + (size_t)B * 16;
  size_t off_total  = off_done + (size_t)B * 4;
  size_t off_Kf     = off_total + (size_t)B * 4;
  size_t off_kw     = (off_Kf + (size_t)B * 4 + 255) & ~(size_t)255;
  size_t off_obox   = (off_kw + (size_t)B * 64 * 8 + 255) & ~(size_t)255;
  size_t off_area   = off_obox + (size_t)B * NBOX * 16;
  size_t off_keys   = (off_area + (size_t)B * NBOX * 4 + 255) & ~(size_t)255;
  size_t off_tr     = (off_keys + (size_t)B * NBOX * 8 + 255) & ~(size_t)255;
  size_t sz_tr      = (size_t)B * 16 * NBOX * 8;   // 8 MiB at B=16
  size_t need_fast  = off_tr + sz_tr;

  int*    ws_sorted = (int*)((char*)d_ws + off_sorted);
  int*    ws_V      = (int*)((char*)d_ws + off_V);
  int*    ws_Vseg   = (int*)((char*)d_ws + off_Vseg);
  int*    ws_done   = (int*)((char*)d_ws + off_done);
  int*    ws_total  = (int*)((char*)d_ws + off_total);
  int*    ws_K      = (int*)((char*)d_ws + off_Kf);
  ull*    ws_keptw  = (ull*)((char*)d_ws + off_kw);
  float4* obox      = (float4*)((char*)d_ws + off_obox);
  float*  area      = (float*)((char*)d_ws + off_area);
  ull*    ws_keys   = (ull*)((char*)d_ws + off_keys);
  ull*    trans     = (ull*)((char*)d_ws + off_tr);

  if (ws_size >= need_fast && N == NBOX) {
    sort_seg<<<dim3(4, B), dim3(256), 0, stream>>>(scores, labels, cls_w,
                                                   ws_keys, ws_Vseg, N);
    merge_top<<<dim3(B), dim3(512), 0, stream>>>(ws_keys, ws_Vseg, boxes, labels,
                                                 img_sz, ws_sorted, ws_V, ws_done,
                                                 obox, area, N);
    suptr0<<<dim3(136, B), dim3(256), 0, stream>>>(
        obox, area, nms_thresh, ws_V, trans);
    resolve0<<<dim3(B), dim3(NTHR), 0, stream>>>(
        boxes, scores, labels, img_sz, ws_V, trans,
        ws_done, ws_total, ws_keptw, ws_K, ws_sorted, (float*)d_out, B, N);
    cleanup_kernel<<<dim3(B), dim3(NTHR), 0, stream>>>(
        ws_keys, boxes, scores, labels, img_sz, nms_thresh, ws_V,
        ws_done, ws_total, ws_keptw, obox, ws_K, (float*)d_out, B, N);
  } else {
    // fallback: full sort via S1+M+R1, then monolithic NMS
    sort_seg<<<dim3(4, B), dim3(256), 0, stream>>>(scores, labels, cls_w,
                                                   ws_keys, ws_Vseg, N);
    merge_top<<<dim3(B), dim3(512), 0, stream>>>(ws_keys, ws_Vseg, boxes, labels,
                                                 img_sz, ws_sorted, ws_V, ws_done,
                                                 obox, area, N);
    merge_full<<<dim3(B), dim3(NTHR), 0, stream>>>(
        ws_keys, boxes, labels, img_sz, ws_sorted, obox, area, N);
    float4* ws_ovf = (float4*)((char*)d_ws + off_keys);  // reuse keys tail region
    nms_kernel<<<dim3(B), dim3(NTHR), 0, stream>>>(boxes, scores, labels,
                                                   nms_thresh, cls_w, img_sz,
                                                   (float*)d_out, B, N,
                                                   ws_sorted, ws_V, ws_ovf);
  }
}